// Round 15
// baseline (604.702 us; speedup 1.0000x reference)
//
#include <hip/hip_runtime.h>
#include <hip/hip_bf16.h>
#include <math.h>

#define HID 128
#define SLOPE 0.01f
#define LN_EPS 1e-5f
#define NB_SCAN 256
#define NT_SCAN 256
#define BSHIFT 6     // 64 dst nodes per bucket
#define SUBLOG 5     // 32 sub-segments per bucket

__device__ __forceinline__ float bf16lo(unsigned int v) {
  unsigned int b = v << 16;
  return __builtin_bit_cast(float, b);
}
__device__ __forceinline__ float bf16hi(unsigned int v) {
  unsigned int b = v & 0xFFFF0000u;
  return __builtin_bit_cast(float, b);
}
__device__ __forceinline__ unsigned int pack_bf16(float lo, float hi) {
  __hip_bfloat16 a = __float2bfloat16(lo);
  __hip_bfloat16 b = __float2bfloat16(hi);
  return (unsigned int)__builtin_bit_cast(unsigned short, a) |
         ((unsigned int)__builtin_bit_cast(unsigned short, b) << 16);
}
__device__ __host__ __forceinline__ int pad16(int c) { return (c + 15) & ~15; }
// sub-segment id: low 3 bits == (blockIdx%8) in the 256-thread scatter grid,
// so each segment is written by a single XCD (deterministic fn of edge index).
__device__ __forceinline__ int subidx(int e) {
  return ((e >> 8) & 7) | (((e >> 11) & 3) << 3);
}

__global__ void zero_int_kernel(int* __restrict__ p, int n) {
  int i = blockIdx.x * blockDim.x + threadIdx.x;
  if (i < n) p[i] = 0;
}

__global__ void hist2_kernel(const int* __restrict__ dst, int* __restrict__ cnt2, int E) {
  int e = blockIdx.x * blockDim.x + threadIdx.x;
  if (e >= E) return;
  int key = ((dst[e] >> BSHIFT) << SUBLOG) | subidx(e);
  atomicAdd(&cnt2[key], 1);
}

// dual 3-pass exclusive scan (unpadded U, padded-to-64B P) over m counts
__global__ void scan_pass1(const int* __restrict__ cnt, int* __restrict__ bsU,
                           int* __restrict__ bsP, int m) {
  __shared__ int su[NT_SCAN];
  __shared__ int sp[NT_SCAN];
  int K = (m + NB_SCAN * NT_SCAN - 1) / (NB_SCAN * NT_SCAN);
  int t = threadIdx.x, b = blockIdx.x;
  int beg = (b * NT_SCAN + t) * K;
  int end = min(beg + K, m);
  int sU = 0, sP = 0;
  for (int i = beg; i < end; ++i) { int c = cnt[i]; sU += c; sP += pad16(c); }
  su[t] = sU; sp[t] = sP;
  __syncthreads();
  for (int off = NT_SCAN / 2; off > 0; off >>= 1) {
    if (t < off) { su[t] += su[t + off]; sp[t] += sp[t + off]; }
    __syncthreads();
  }
  if (t == 0) { bsU[b] = su[0]; bsP[b] = sp[0]; }
}

__global__ void scan_pass2(int* __restrict__ bsU, int* __restrict__ bsP) {
  __shared__ int su[NB_SCAN];
  __shared__ int sp[NB_SCAN];
  int t = threadIdx.x;
  su[t] = bsU[t]; sp[t] = bsP[t];
  __syncthreads();
  for (int off = 1; off < NB_SCAN; off <<= 1) {
    int vU = (t >= off) ? su[t - off] : 0;
    int vP = (t >= off) ? sp[t - off] : 0;
    __syncthreads();
    su[t] += vU; sp[t] += vP;
    __syncthreads();
  }
  bsU[t] = (t == 0) ? 0 : su[t - 1];
  bsP[t] = (t == 0) ? 0 : sp[t - 1];
}

// pass3: write rowptr2u (unpadded), rowptr2p (padded) and bcur (=rowptr2p)
__global__ void scan_pass3(const int* __restrict__ cnt, const int* __restrict__ bsU,
                           const int* __restrict__ bsP, int* __restrict__ rowptr2u,
                           int* __restrict__ rowptr2p, int* __restrict__ bcur, int m) {
  __shared__ int su[NT_SCAN];
  __shared__ int sp[NT_SCAN];
  int K = (m + NB_SCAN * NT_SCAN - 1) / (NB_SCAN * NT_SCAN);
  int t = threadIdx.x, b = blockIdx.x;
  int beg = (b * NT_SCAN + t) * K;
  int end = min(beg + K, m);
  int sU = 0, sP = 0;
  for (int i = beg; i < end; ++i) { int c = cnt[i]; sU += c; sP += pad16(c); }
  su[t] = sU; sp[t] = sP;
  __syncthreads();
  for (int off = 1; off < NT_SCAN; off <<= 1) {
    int vU = (t >= off) ? su[t - off] : 0;
    int vP = (t >= off) ? sp[t - off] : 0;
    __syncthreads();
    su[t] += vU; sp[t] += vP;
    __syncthreads();
  }
  int preU = bsU[b] + ((t == 0) ? 0 : su[t - 1]);
  int preP = bsP[b] + ((t == 0) ? 0 : sp[t - 1]);
  for (int i = beg; i < end; ++i) {
    int c = cnt[i];
    rowptr2u[i] = preU;
    rowptr2p[i] = preP;
    bcur[i] = preP;
    preU += c;
    preP += pad16(c);
    if (i == m - 1) { rowptr2u[m] = preU; rowptr2p[m] = preP; }
  }
}

// scatter packed (src<<6 | dst&63) into 64B-aligned, XCD-owned sub-segments
__global__ void bucket_scatter_kernel(const int* __restrict__ src, const int* __restrict__ dst,
                                      int* __restrict__ bcur, unsigned int* __restrict__ ebuf,
                                      int E) {
  int e = blockIdx.x * blockDim.x + threadIdx.x;
  if (e >= E) return;
  int s = src[e], d = dst[e];
  int key = ((d >> BSHIFT) << SUBLOG) | subidx(e);
  int pos = atomicAdd(&bcur[key], 1);
  ebuf[pos] = ((unsigned)s << 6) | ((unsigned)d & 63);
}

// per-bucket: degree count in LDS (per-sub ranges) -> per-node rowptr
// (unpadded bucket base + wave scan), dinv.  One block per bucket.
__global__ __launch_bounds__(256) void deg_rowptr_kernel(
    const unsigned int* __restrict__ ebuf, const int* __restrict__ rowptr2p,
    const int* __restrict__ cnt2, const int* __restrict__ rowptr2u,
    int* __restrict__ rowptr, float* __restrict__ dinv,
    int n, int nbuck, int nkey) {
  __shared__ int sdeg[64];
  int b = blockIdx.x, tid = threadIdx.x;
  int wid = tid >> 6, lane = tid & 63;
  if (tid < 64) sdeg[tid] = 0;
  __syncthreads();
  for (int sub = wid; sub < (1 << SUBLOG); sub += 4) {
    int key = (b << SUBLOG) | sub;
    int beg = rowptr2p[key], c = cnt2[key];
    for (int j = lane; j < c; j += 64) atomicAdd(&sdeg[ebuf[beg + j] & 63], 1);
  }
  __syncthreads();
  if (tid < 64) {
    int deg = sdeg[tid];
    int s = deg;
#pragma unroll
    for (int off = 1; off < 64; off <<= 1) {
      int v = __shfl_up(s, off);
      if (tid >= off) s += v;
    }
    int excl = s - deg;
    int nd = (b << BSHIFT) + tid;
    if (nd < n) {
      rowptr[nd] = rowptr2u[b << SUBLOG] + excl;
      dinv[nd] = rsqrtf((float)(deg + 1));
    }
    if (b == nbuck - 1 && tid == 0) rowptr[n] = rowptr2u[nkey];
  }
}

// per-bucket CSR fill: LDS cursors, packed (unpadded) ecol writes in a ~15KB window
__global__ __launch_bounds__(256) void fill_bucket_kernel(
    const unsigned int* __restrict__ ebuf, const int* __restrict__ rowptr2p,
    const int* __restrict__ cnt2, const int* __restrict__ rowptr,
    const float* __restrict__ dinv, uint2* __restrict__ ecol, int n) {
  __shared__ int scur[64];
  __shared__ int srow[64];
  __shared__ float sdinv[64];
  int b = blockIdx.x, tid = threadIdx.x;
  int wid = tid >> 6, lane = tid & 63;
  if (tid < 64) {
    scur[tid] = 0;
    int nd = (b << BSHIFT) + tid;
    srow[tid] = (nd < n) ? rowptr[nd] : 0;
    sdinv[tid] = (nd < n) ? dinv[nd] : 0.0f;
  }
  __syncthreads();
  for (int sub = wid; sub < (1 << SUBLOG); sub += 4) {
    int key = (b << SUBLOG) | sub;
    int beg = rowptr2p[key], c = cnt2[key];
    for (int j = lane; j < c; j += 64) {
      unsigned int v = ebuf[beg + j];
      int ndl = (int)(v & 63);
      int s = (int)(v >> 6);
      int pos = atomicAdd(&scur[ndl], 1);
      float w = dinv[s] * sdinv[ndl];
      ecol[srow[ndl] + pos] = make_uint2((unsigned)s, __builtin_bit_cast(unsigned int, w));
    }
  }
}

// Multi-row dense: out[r][j] = bias[j] + sum_k feat[r][k]*W[k][j].
// W column j staged in REGISTERS (packed bf16 pairs); rows staged in LDS.
template<int DIM, int ROWS, bool BF16OUT>
__global__ __launch_bounds__(256) void dense_mr_kernel(
    const float* __restrict__ feat, const float* __restrict__ W,
    const float* __restrict__ bias,
    float* __restrict__ outf, unsigned int* __restrict__ outb, int nrows) {
  __shared__ float sf[ROWS * DIM];
  int tid = threadIdx.x;
  int base = blockIdx.x * ROWS;
  int j = tid & 127;
  int rr = tid >> 7;

  unsigned int wreg[DIM / 2];
#pragma unroll
  for (int k2 = 0; k2 < DIM / 2; ++k2) {
    wreg[k2] = pack_bf16(W[(size_t)(2 * k2) * HID + j],
                         W[(size_t)(2 * k2 + 1) * HID + j]);
  }

  int nr = min(ROWS, nrows - base);
  int tot = nr * DIM;
  const float* fp = feat + (size_t)base * DIM;
  for (int i = tid * 4; i < tot; i += 1024) {
    *reinterpret_cast<float4*>(&sf[i]) = *reinterpret_cast<const float4*>(&fp[i]);
  }
  __syncthreads();

  float bj = bias ? bias[j] : 0.0f;
  for (int r = rr; r < nr; r += 2) {
    float acc = bj;
    const float4* row4 = reinterpret_cast<const float4*>(&sf[r * DIM]);
#pragma unroll
    for (int k4 = 0; k4 < DIM / 4; ++k4) {
      float4 xv = row4[k4];
      unsigned int wa = wreg[2 * k4];
      unsigned int wb = wreg[2 * k4 + 1];
      acc = fmaf(xv.x, bf16lo(wa), acc);
      acc = fmaf(xv.y, bf16hi(wa), acc);
      acc = fmaf(xv.z, bf16lo(wb), acc);
      acc = fmaf(xv.w, bf16hi(wb), acc);
    }
    if (BF16OUT) {
      float other = __shfl_xor(acc, 1);
      if ((j & 1) == 0) {
        outb[((size_t)(base + r) * HID + j) >> 1] = pack_bf16(acc, other);
      }
    } else {
      outf[(size_t)(base + r) * HID + j] = acc;
    }
  }
}

// One wave per dst node; 4 lane-groups of 16, each group takes one edge per
// iteration: one uint2 (src, weight) broadcast load + one uint4 row load/lane.
// Cross-group combine once at the end, then self-loop + bias + LN + LeakyReLU
// (+ head projection).  (R9-form summation order preserved.)
template<bool PROJ>
__global__ void gather_norm_kernel(const int* __restrict__ rowptr,
                                   const uint2* __restrict__ ecol,  // (src, w) per edge
                                   const uint4* __restrict__ xwb4,  // n x 16 uint4
                                   const float* __restrict__ dinv,
                                   const float* __restrict__ cb,
                                   const float* __restrict__ g,
                                   const float* __restrict__ b,
                                   const float* __restrict__ eW,
                                   const float* __restrict__ rW,
                                   float* __restrict__ outx,
                                   float4* __restrict__ table, int n_nodes) {
  int d = blockIdx.x * 4 + (threadIdx.x >> 6);
  if (d >= n_nodes) return;
  int lane = threadIdx.x & 63;
  int grp = lane >> 4;    // 0..3: which edge in the 4-edge iteration
  int t = lane & 15;      // sublane: channels 8t..8t+7

  float acc[8];
#pragma unroll
  for (int k = 0; k < 8; ++k) acc[k] = 0.0f;

  float wd = dinv[d];
  int beg = rowptr[d], end = rowptr[d + 1];
  for (int j = beg + grp; j < end; j += 4) {
    uint2 e = ecol[j];
    float w = __builtin_bit_cast(float, e.y);
    uint4 v = xwb4[(size_t)e.x * 16 + t];
    acc[0] = fmaf(bf16lo(v.x), w, acc[0]);
    acc[1] = fmaf(bf16hi(v.x), w, acc[1]);
    acc[2] = fmaf(bf16lo(v.y), w, acc[2]);
    acc[3] = fmaf(bf16hi(v.y), w, acc[3]);
    acc[4] = fmaf(bf16lo(v.z), w, acc[4]);
    acc[5] = fmaf(bf16hi(v.z), w, acc[5]);
    acc[6] = fmaf(bf16lo(v.w), w, acc[6]);
    acc[7] = fmaf(bf16hi(v.w), w, acc[7]);
  }
#pragma unroll
  for (int k = 0; k < 8; ++k) {
    acc[k] += __shfl_xor(acc[k], 16);
    acc[k] += __shfl_xor(acc[k], 32);
  }
  // self loop + conv bias
  {
    float wself = wd * wd;
    uint4 v = xwb4[(size_t)d * 16 + t];
    acc[0] = fmaf(bf16lo(v.x), wself, acc[0]);
    acc[1] = fmaf(bf16hi(v.x), wself, acc[1]);
    acc[2] = fmaf(bf16lo(v.y), wself, acc[2]);
    acc[3] = fmaf(bf16hi(v.y), wself, acc[3]);
    acc[4] = fmaf(bf16lo(v.z), wself, acc[4]);
    acc[5] = fmaf(bf16hi(v.z), wself, acc[5]);
    acc[6] = fmaf(bf16lo(v.w), wself, acc[6]);
    acc[7] = fmaf(bf16hi(v.w), wself, acc[7]);
    float4 c0 = *reinterpret_cast<const float4*>(cb + 8 * t);
    float4 c1 = *reinterpret_cast<const float4*>(cb + 8 * t + 4);
    acc[0] += c0.x; acc[1] += c0.y; acc[2] += c0.z; acc[3] += c0.w;
    acc[4] += c1.x; acc[5] += c1.y; acc[6] += c1.z; acc[7] += c1.w;
  }
  // LayerNorm over 128 channels (16 sublanes x 8)
  float s = acc[0] + acc[1] + acc[2] + acc[3] + acc[4] + acc[5] + acc[6] + acc[7];
#pragma unroll
  for (int m = 1; m < 16; m <<= 1) s += __shfl_xor(s, m);
  float mu = s * (1.0f / HID);
  float sq = 0.0f;
#pragma unroll
  for (int k = 0; k < 8; ++k) {
    acc[k] -= mu;
    sq = fmaf(acc[k], acc[k], sq);
  }
#pragma unroll
  for (int m = 1; m < 16; m <<= 1) sq += __shfl_xor(sq, m);
  float rs = rsqrtf(sq * (1.0f / HID) + LN_EPS);
  float4 g0 = *reinterpret_cast<const float4*>(g + 8 * t);
  float4 g1 = *reinterpret_cast<const float4*>(g + 8 * t + 4);
  float4 b0 = *reinterpret_cast<const float4*>(b + 8 * t);
  float4 b1 = *reinterpret_cast<const float4*>(b + 8 * t + 4);
  float o[8];
  o[0] = acc[0] * rs * g0.x + b0.x;
  o[1] = acc[1] * rs * g0.y + b0.y;
  o[2] = acc[2] * rs * g0.z + b0.z;
  o[3] = acc[3] * rs * g0.w + b0.w;
  o[4] = acc[4] * rs * g1.x + b1.x;
  o[5] = acc[5] * rs * g1.y + b1.y;
  o[6] = acc[6] * rs * g1.z + b1.z;
  o[7] = acc[7] * rs * g1.w + b1.w;
#pragma unroll
  for (int k = 0; k < 8; ++k) o[k] = o[k] >= 0.0f ? o[k] : SLOPE * o[k];

  if (!PROJ) {
    if (grp == 0) {
      float4* op = reinterpret_cast<float4*>(outx + (size_t)d * HID + 8 * t);
      op[0] = make_float4(o[0], o[1], o[2], o[3]);
      op[1] = make_float4(o[4], o[5], o[6], o[7]);
    }
  } else {
    float4 eu0 = *reinterpret_cast<const float4*>(eW + 8 * t);
    float4 eu1 = *reinterpret_cast<const float4*>(eW + 8 * t + 4);
    float4 ef0 = *reinterpret_cast<const float4*>(eW + HID + 8 * t);
    float4 ef1 = *reinterpret_cast<const float4*>(eW + HID + 8 * t + 4);
    float4 ru0 = *reinterpret_cast<const float4*>(rW + 8 * t);
    float4 ru1 = *reinterpret_cast<const float4*>(rW + 8 * t + 4);
    float4 rf0 = *reinterpret_cast<const float4*>(rW + HID + 8 * t);
    float4 rf1 = *reinterpret_cast<const float4*>(rW + HID + 8 * t + 4);
    float pa = o[0]*eu0.x + o[1]*eu0.y + o[2]*eu0.z + o[3]*eu0.w
             + o[4]*eu1.x + o[5]*eu1.y + o[6]*eu1.z + o[7]*eu1.w;
    float pb = o[0]*ef0.x + o[1]*ef0.y + o[2]*ef0.z + o[3]*ef0.w
             + o[4]*ef1.x + o[5]*ef1.y + o[6]*ef1.z + o[7]*ef1.w;
    float pc = o[0]*ru0.x + o[1]*ru0.y + o[2]*ru0.z + o[3]*ru0.w
             + o[4]*ru1.x + o[5]*ru1.y + o[6]*ru1.z + o[7]*ru1.w;
    float pd = o[0]*rf0.x + o[1]*rf0.y + o[2]*rf0.z + o[3]*rf0.w
             + o[4]*rf1.x + o[5]*rf1.y + o[6]*rf1.z + o[7]*rf1.w;
#pragma unroll
    for (int m = 1; m < 16; m <<= 1) {
      pa += __shfl_xor(pa, m);
      pb += __shfl_xor(pb, m);
      pc += __shfl_xor(pc, m);
      pd += __shfl_xor(pd, m);
    }
    if (lane == 0) table[d] = make_float4(pa, pb, pc, pd);
  }
}

// one thread per prediction pair
__global__ void pair_kernel(const int* __restrict__ eu, const int* __restrict__ ef,
                            const float4* __restrict__ table,
                            const float* __restrict__ eb, const float* __restrict__ rb,
                            float* __restrict__ out_exist, float* __restrict__ out_rating,
                            int Ep) {
  int i = blockIdx.x * blockDim.x + threadIdx.x;
  if (i >= Ep) return;
  float4 tu = table[eu[i]];
  float4 tf = table[ef[i]];
  float pe = tu.x + tf.y + eb[0];
  float pr = tu.z + tf.w + rb[0];
  out_exist[i]  = 1.0f / (1.0f + expf(-pe));
  out_rating[i] = 1.0f + 4.0f / (1.0f + expf(-pr));
}

extern "C" void kernel_launch(void* const* d_in, const int* in_sizes, int n_in,
                              void* d_out, int out_size, void* d_ws, size_t ws_size,
                              hipStream_t stream) {
  const float* u_feat = (const float*)d_in[0];
  const float* f_feat = (const float*)d_in[1];
  const int*   ei     = (const int*)d_in[2];
  const int*   eu     = (const int*)d_in[3];
  const int*   ef     = (const int*)d_in[4];
  const float* u_W  = (const float*)d_in[5];
  const float* u_b  = (const float*)d_in[6];
  const float* f_W  = (const float*)d_in[7];
  const float* f_b  = (const float*)d_in[8];
  const float* c1_W = (const float*)d_in[9];
  const float* c1_b = (const float*)d_in[10];
  const float* c2_W = (const float*)d_in[11];
  const float* c2_b = (const float*)d_in[12];
  const float* n1_g = (const float*)d_in[13];
  const float* n1_b = (const float*)d_in[14];
  const float* n2_g = (const float*)d_in[15];
  const float* n2_b = (const float*)d_in[16];
  const float* e_W  = (const float*)d_in[17];
  const float* e_b  = (const float*)d_in[18];
  const float* r_W  = (const float*)d_in[19];
  const float* r_b  = (const float*)d_in[20];

  int n_u = in_sizes[0] / 64;
  int n_f = in_sizes[1] / HID;
  int n   = n_u + n_f;
  int E   = in_sizes[2] / 2;
  int Ep  = in_sizes[3];
  int nbuck = (n + (1 << BSHIFT) - 1) >> BSHIFT;
  int nkey  = nbuck << SUBLOG;
  int ebuf_cap = E + 16 * nkey;   // padded capacity

  const int* src = ei;
  const int* dst = ei + E;

  float*        x        = (float*)d_ws;                           // n*HID f32
  unsigned int* xwb      = (unsigned int*)(x + (size_t)n * HID);   // n*HID/2 uint
  float4*       table    = (float4*)(xwb + (size_t)n * (HID / 2)); // n float4
  unsigned int* ebuf     = (unsigned int*)(table + n);             // ebuf_cap uint
  uint2*        ecol     = (uint2*)(ebuf + ebuf_cap);              // E uint2
  float*        dinv     = (float*)(ecol + E);                     // n f32
  int*          rowptr   = (int*)(dinv + n);                       // n+1 int
  int*          cnt2     = rowptr + n + 1;                         // nkey int
  int*          rowptr2u = cnt2 + nkey;                            // nkey+1 int
  int*          rowptr2p = rowptr2u + nkey + 1;                    // nkey+1 int
  int*          bsU      = rowptr2p + nkey + 1;                    // NB_SCAN int
  int*          bsP      = bsU + NB_SCAN;                          // NB_SCAN int
  int*          bcur     = bsP + NB_SCAN;                          // nkey int

  // ---- bucketed edge sort (64B-aligned, XCD-owned sub-segments) ----
  zero_int_kernel<<<(nkey + 255) / 256, 256, 0, stream>>>(cnt2, nkey);
  hist2_kernel<<<(E + 255) / 256, 256, 0, stream>>>(dst, cnt2, E);
  scan_pass1<<<NB_SCAN, NT_SCAN, 0, stream>>>(cnt2, bsU, bsP, nkey);
  scan_pass2<<<1, NB_SCAN, 0, stream>>>(bsU, bsP);
  scan_pass3<<<NB_SCAN, NT_SCAN, 0, stream>>>(cnt2, bsU, bsP, rowptr2u, rowptr2p,
                                              bcur, nkey);
  bucket_scatter_kernel<<<(E + 255) / 256, 256, 0, stream>>>(src, dst, bcur, ebuf, E);

  // ---- per-node rowptr/dinv from bucketed edges, then per-bucket CSR fill ----
  deg_rowptr_kernel<<<nbuck, 256, 0, stream>>>(ebuf, rowptr2p, cnt2, rowptr2u,
                                               rowptr, dinv, n, nbuck, nkey);
  fill_bucket_kernel<<<nbuck, 256, 0, stream>>>(ebuf, rowptr2p, cnt2, rowptr,
                                                dinv, ecol, n);

  // ---- input embeddings (f32 x) ----
  dense_mr_kernel<64, 32, false><<<(n_u + 31) / 32, 256, 0, stream>>>(
      u_feat, u_W, u_b, x, nullptr, n_u);
  dense_mr_kernel<128, 32, false><<<(n_f + 31) / 32, 256, 0, stream>>>(
      f_feat, f_W, f_b, x + (size_t)n_u * HID, nullptr, n_f);

  // ---- layer 1 ----
  dense_mr_kernel<128, 32, true><<<(n + 31) / 32, 256, 0, stream>>>(
      x, c1_W, nullptr, nullptr, xwb, n);
  gather_norm_kernel<false><<<(n + 3) / 4, 256, 0, stream>>>(
      rowptr, ecol, (const uint4*)xwb, dinv, c1_b, n1_g, n1_b,
      nullptr, nullptr, x, nullptr, n);

  // ---- layer 2 (fused prediction-head projection) ----
  dense_mr_kernel<128, 32, true><<<(n + 31) / 32, 256, 0, stream>>>(
      x, c2_W, nullptr, nullptr, xwb, n);
  gather_norm_kernel<true><<<(n + 3) / 4, 256, 0, stream>>>(
      rowptr, ecol, (const uint4*)xwb, dinv, c2_b, n2_g, n2_b,
      e_W, r_W, nullptr, table, n);

  // ---- per-pair combine ----
  float* out_exist  = (float*)d_out;
  float* out_rating = out_exist + Ep;
  pair_kernel<<<(Ep + 255) / 256, 256, 0, stream>>>(eu, ef, table, e_b, r_b,
                                                    out_exist, out_rating, Ep);
}

// Round 16
// 510.230 us; speedup vs baseline: 1.1852x; 1.1852x over previous
//
#include <hip/hip_runtime.h>
#include <hip/hip_bf16.h>
#include <math.h>

#define HID 128
#define SLOPE 0.01f
#define LN_EPS 1e-5f
#define NB_SCAN 256
#define NT_SCAN 256
#define BSHIFT 6     // 64 dst nodes per bucket
#define SUBLOG 5     // 32 sub-segments per bucket

typedef __attribute__((ext_vector_type(8))) short bf16x8;
typedef __attribute__((ext_vector_type(4))) float f32x4;

__device__ __forceinline__ float bf16lo(unsigned int v) {
  unsigned int b = v << 16;
  return __builtin_bit_cast(float, b);
}
__device__ __forceinline__ float bf16hi(unsigned int v) {
  unsigned int b = v & 0xFFFF0000u;
  return __builtin_bit_cast(float, b);
}
__device__ __forceinline__ unsigned int pack_bf16(float lo, float hi) {
  __hip_bfloat16 a = __float2bfloat16(lo);
  __hip_bfloat16 b = __float2bfloat16(hi);
  return (unsigned int)__builtin_bit_cast(unsigned short, a) |
         ((unsigned int)__builtin_bit_cast(unsigned short, b) << 16);
}
// sub-segment id: deterministic fn of edge index (heuristic XCD spread).
__device__ __forceinline__ int subidx(int e) {
  return ((e >> 8) & 7) | (((e >> 11) & 3) << 3);
}

__global__ void zero_int_kernel(int* __restrict__ p, int n) {
  int i = blockIdx.x * blockDim.x + threadIdx.x;
  if (i < n) p[i] = 0;
}

__global__ void hist2_kernel(const int* __restrict__ dst, int* __restrict__ cnt2, int E) {
  int e = blockIdx.x * blockDim.x + threadIdx.x;
  if (e >= E) return;
  int key = ((dst[e] >> BSHIFT) << SUBLOG) | subidx(e);
  atomicAdd(&cnt2[key], 1);
}

// 3-pass exclusive scan over m elements -> rowptr[0..m], rowptr[m]=total
__global__ void scan_pass1(const int* __restrict__ cnt, int* __restrict__ blocksum, int m) {
  __shared__ int ss[NT_SCAN];
  int K = (m + NB_SCAN * NT_SCAN - 1) / (NB_SCAN * NT_SCAN);
  int t = threadIdx.x, b = blockIdx.x;
  int beg = (b * NT_SCAN + t) * K;
  int end = min(beg + K, m);
  int s = 0;
  for (int i = beg; i < end; ++i) s += cnt[i];
  ss[t] = s;
  __syncthreads();
  for (int off = NT_SCAN / 2; off > 0; off >>= 1) {
    if (t < off) ss[t] += ss[t + off];
    __syncthreads();
  }
  if (t == 0) blocksum[b] = ss[0];
}

__global__ void scan_pass2(int* __restrict__ blocksum) {
  __shared__ int ss[NB_SCAN];
  int t = threadIdx.x;
  ss[t] = blocksum[t];
  __syncthreads();
  for (int off = 1; off < NB_SCAN; off <<= 1) {
    int v = (t >= off) ? ss[t - off] : 0;
    __syncthreads();
    ss[t] += v;
    __syncthreads();
  }
  blocksum[t] = (t == 0) ? 0 : ss[t - 1];
}

// pass3: write rowptr (exclusive) AND bucket cursors (same values)
__global__ void scan_pass3(const int* __restrict__ cnt, const int* __restrict__ blockoff,
                           int* __restrict__ rowptr, int* __restrict__ bcur, int m) {
  __shared__ int ss[NT_SCAN];
  int K = (m + NB_SCAN * NT_SCAN - 1) / (NB_SCAN * NT_SCAN);
  int t = threadIdx.x, b = blockIdx.x;
  int beg = (b * NT_SCAN + t) * K;
  int end = min(beg + K, m);
  int s = 0;
  for (int i = beg; i < end; ++i) s += cnt[i];
  ss[t] = s;
  __syncthreads();
  for (int off = 1; off < NT_SCAN; off <<= 1) {
    int v = (t >= off) ? ss[t - off] : 0;
    __syncthreads();
    ss[t] += v;
    __syncthreads();
  }
  int pre = blockoff[b] + ((t == 0) ? 0 : ss[t - 1]);
  for (int i = beg; i < end; ++i) {
    rowptr[i] = pre;
    bcur[i] = pre;
    pre += cnt[i];
    if (i == m - 1) rowptr[m] = pre;
  }
}

// scatter packed (src<<6 | dst&63) into dst-bucketed sub-segments
__global__ void bucket_scatter_kernel(const int* __restrict__ src, const int* __restrict__ dst,
                                      int* __restrict__ bcur, unsigned int* __restrict__ ebuf,
                                      int E) {
  int e = blockIdx.x * blockDim.x + threadIdx.x;
  if (e >= E) return;
  int s = src[e], d = dst[e];
  int key = ((d >> BSHIFT) << SUBLOG) | subidx(e);
  int pos = atomicAdd(&bcur[key], 1);
  ebuf[pos] = ((unsigned)s << 6) | ((unsigned)d & 63);
}

// per-bucket: degree count in LDS -> per-node rowptr (bucket base + wave scan),
// dinv.  One block per bucket.
__global__ __launch_bounds__(256) void deg_rowptr_kernel(
    const unsigned int* __restrict__ ebuf, const int* __restrict__ rowptr2,
    int* __restrict__ rowptr, float* __restrict__ dinv,
    int n, int nbuck, int E) {
  __shared__ int sdeg[64];
  int b = blockIdx.x, tid = threadIdx.x;
  if (tid < 64) sdeg[tid] = 0;
  __syncthreads();
  int beg = rowptr2[b << SUBLOG], end = rowptr2[(b + 1) << SUBLOG];
  for (int j = beg + tid; j < end; j += 256) atomicAdd(&sdeg[ebuf[j] & 63], 1);
  __syncthreads();
  if (tid < 64) {
    int deg = sdeg[tid];
    int s = deg;
#pragma unroll
    for (int off = 1; off < 64; off <<= 1) {
      int v = __shfl_up(s, off);
      if (tid >= off) s += v;
    }
    int excl = s - deg;
    int nd = (b << BSHIFT) + tid;
    if (nd < n) {
      rowptr[nd] = beg + excl;
      dinv[nd] = rsqrtf((float)(deg + 1));
    }
    if (b == nbuck - 1 && tid == 0) rowptr[n] = E;
  }
}

// per-bucket CSR fill: LDS cursors, ecol writes in a ~15KB window
__global__ __launch_bounds__(256) void fill_bucket_kernel(
    const unsigned int* __restrict__ ebuf, const int* __restrict__ rowptr2,
    const int* __restrict__ rowptr, const float* __restrict__ dinv,
    uint2* __restrict__ ecol, int n) {
  __shared__ int scur[64];
  __shared__ int srow[64];
  __shared__ float sdinv[64];
  int b = blockIdx.x, tid = threadIdx.x;
  if (tid < 64) {
    scur[tid] = 0;
    int nd = (b << BSHIFT) + tid;
    srow[tid] = (nd < n) ? rowptr[nd] : 0;
    sdinv[tid] = (nd < n) ? dinv[nd] : 0.0f;
  }
  __syncthreads();
  int beg = rowptr2[b << SUBLOG], end = rowptr2[(b + 1) << SUBLOG];
  for (int j = beg + tid; j < end; j += 256) {
    unsigned int v = ebuf[j];
    int ndl = (int)(v & 63);
    int s = (int)(v >> 6);
    int pos = atomicAdd(&scur[ndl], 1);
    float w = dinv[s] * sdinv[ndl];
    ecol[srow[ndl] + pos] = make_uint2((unsigned)s, __builtin_bit_cast(unsigned int, w));
  }
}

// Transpose+pack W[K][128] f32 -> Wt[128][K/2] packed bf16 (k-pairs)
__global__ void wt_pack_kernel(const float* __restrict__ W, unsigned int* __restrict__ Wt,
                               int K) {
  int idx = blockIdx.x * 256 + threadIdx.x;
  int total = 128 * (K / 2);
  if (idx >= total) return;
  int col = idx & 127;
  int k2 = idx >> 7;
  Wt[(size_t)col * (K / 2) + k2] =
      pack_bf16(W[(size_t)(2 * k2) * 128 + col], W[(size_t)(2 * k2 + 1) * 128 + col]);
}

// MFMA dense: out[r][j] = bias[j] + sum_k feat[r][k]*bf16(W[k][j]).
// x split hi/lo bf16 (2 MFMAs) to preserve f32-level input fidelity.
// 4 waves/block; wave w: rows base+16*(w&1), cols 64*(w>>1)..+64 (4 16x16 tiles).
// No LDS; A from global f32, B from pre-packed Wt (L2-resident).
template<int K, bool BF16OUT>
__global__ __launch_bounds__(256) void dense_mfma_kernel(
    const float* __restrict__ feat, const unsigned int* __restrict__ Wt,
    const float* __restrict__ bias,
    float* __restrict__ outf, __hip_bfloat16* __restrict__ outb, int nrows) {
  int tid = threadIdx.x;
  int wid = tid >> 6, lane = tid & 63;
  int l15 = lane & 15, lk = lane >> 4;
  int rowbase = blockIdx.x * 32 + 16 * (wid & 1);
  int colbase = 64 * (wid >> 1);

  f32x4 acc0 = {}, acc1 = {}, acc2 = {}, acc3 = {};

  int row = rowbase + l15;
  int rrow = min(row, nrows - 1);
  const float* ap0 = feat + (size_t)rrow * K + lk * 8;

#pragma unroll
  for (int kb = 0; kb < K / 32; ++kb) {
    const float* ap = ap0 + kb * 32;
    float4 a0 = *reinterpret_cast<const float4*>(ap);
    float4 a1 = *reinterpret_cast<const float4*>(ap + 4);
    float af0 = a0.x, af1 = a0.y, af2 = a0.z, af3 = a0.w;
    float af4 = a1.x, af5 = a1.y, af6 = a1.z, af7 = a1.w;
    // hi = truncate-to-bf16 (bit mask), lo = residual (bf16 RNE)
    unsigned int b0 = __builtin_bit_cast(unsigned int, af0);
    unsigned int b1 = __builtin_bit_cast(unsigned int, af1);
    unsigned int b2 = __builtin_bit_cast(unsigned int, af2);
    unsigned int b3 = __builtin_bit_cast(unsigned int, af3);
    unsigned int b4 = __builtin_bit_cast(unsigned int, af4);
    unsigned int b5 = __builtin_bit_cast(unsigned int, af5);
    unsigned int b6 = __builtin_bit_cast(unsigned int, af6);
    unsigned int b7 = __builtin_bit_cast(unsigned int, af7);
    uint4 hv;
    hv.x = (b0 >> 16) | (b1 & 0xFFFF0000u);
    hv.y = (b2 >> 16) | (b3 & 0xFFFF0000u);
    hv.z = (b4 >> 16) | (b5 & 0xFFFF0000u);
    hv.w = (b6 >> 16) | (b7 & 0xFFFF0000u);
    uint4 lv;
    lv.x = pack_bf16(af0 - bf16hi(b0 & 0xFFFF0000u ? b0 : b0),  // placeholder, replaced below
                     0.0f);
    // (recompute cleanly)
    {
      float h0 = __builtin_bit_cast(float, b0 & 0xFFFF0000u);
      float h1 = __builtin_bit_cast(float, b1 & 0xFFFF0000u);
      float h2 = __builtin_bit_cast(float, b2 & 0xFFFF0000u);
      float h3 = __builtin_bit_cast(float, b3 & 0xFFFF0000u);
      float h4 = __builtin_bit_cast(float, b4 & 0xFFFF0000u);
      float h5 = __builtin_bit_cast(float, b5 & 0xFFFF0000u);
      float h6 = __builtin_bit_cast(float, b6 & 0xFFFF0000u);
      float h7 = __builtin_bit_cast(float, b7 & 0xFFFF0000u);
      lv.x = pack_bf16(af0 - h0, af1 - h1);
      lv.y = pack_bf16(af2 - h2, af3 - h3);
      lv.z = pack_bf16(af4 - h4, af5 - h5);
      lv.w = pack_bf16(af6 - h6, af7 - h7);
    }
    bf16x8 ahi = __builtin_bit_cast(bf16x8, hv);
    bf16x8 alo = __builtin_bit_cast(bf16x8, lv);

    const unsigned int* wrow = Wt + (size_t)(colbase + l15) * (K / 2) + kb * 16 + lk * 4;
    bf16x8 bf0 = __builtin_bit_cast(bf16x8, *reinterpret_cast<const uint4*>(wrow));
    bf16x8 bf1 = __builtin_bit_cast(bf16x8, *reinterpret_cast<const uint4*>(wrow + 16 * (K / 2)));
    bf16x8 bf2 = __builtin_bit_cast(bf16x8, *reinterpret_cast<const uint4*>(wrow + 32 * (K / 2)));
    bf16x8 bf3 = __builtin_bit_cast(bf16x8, *reinterpret_cast<const uint4*>(wrow + 48 * (K / 2)));
    acc0 = __builtin_amdgcn_mfma_f32_16x16x32_bf16(ahi, bf0, acc0, 0, 0, 0);
    acc0 = __builtin_amdgcn_mfma_f32_16x16x32_bf16(alo, bf0, acc0, 0, 0, 0);
    acc1 = __builtin_amdgcn_mfma_f32_16x16x32_bf16(ahi, bf1, acc1, 0, 0, 0);
    acc1 = __builtin_amdgcn_mfma_f32_16x16x32_bf16(alo, bf1, acc1, 0, 0, 0);
    acc2 = __builtin_amdgcn_mfma_f32_16x16x32_bf16(ahi, bf2, acc2, 0, 0, 0);
    acc2 = __builtin_amdgcn_mfma_f32_16x16x32_bf16(alo, bf2, acc2, 0, 0, 0);
    acc3 = __builtin_amdgcn_mfma_f32_16x16x32_bf16(ahi, bf3, acc3, 0, 0, 0);
    acc3 = __builtin_amdgcn_mfma_f32_16x16x32_bf16(alo, bf3, acc3, 0, 0, 0);
  }

  // store: D tile t at cols colbase+16t; col=lane&15, row=(lane>>4)*4+r
#pragma unroll
  for (int t = 0; t < 4; ++t) {
    int col = colbase + 16 * t + l15;
    float bv = bias ? bias[col] : 0.0f;
    f32x4 a = (t == 0) ? acc0 : (t == 1) ? acc1 : (t == 2) ? acc2 : acc3;
#pragma unroll
    for (int r = 0; r < 4; ++r) {
      int orow = rowbase + lk * 4 + r;
      if (orow < nrows) {
        float v = a[r] + bv;
        if (BF16OUT) outb[(size_t)orow * HID + col] = __float2bfloat16(v);
        else         outf[(size_t)orow * HID + col] = v;
      }
    }
  }
}

// One wave per dst node; 4 lane-groups of 16, each group one edge/iter:
// uint2 (src, weight) broadcast load + uint4 row load/lane.  (R9-form order.)
template<bool PROJ>
__global__ void gather_norm_kernel(const int* __restrict__ rowptr,
                                   const uint2* __restrict__ ecol,
                                   const uint4* __restrict__ xwb4,
                                   const float* __restrict__ dinv,
                                   const float* __restrict__ cb,
                                   const float* __restrict__ g,
                                   const float* __restrict__ b,
                                   const float* __restrict__ eW,
                                   const float* __restrict__ rW,
                                   float* __restrict__ outx,
                                   float4* __restrict__ table, int n_nodes) {
  int d = blockIdx.x * 4 + (threadIdx.x >> 6);
  if (d >= n_nodes) return;
  int lane = threadIdx.x & 63;
  int grp = lane >> 4;
  int t = lane & 15;

  float acc[8];
#pragma unroll
  for (int k = 0; k < 8; ++k) acc[k] = 0.0f;

  float wd = dinv[d];
  int beg = rowptr[d], end = rowptr[d + 1];
  for (int j = beg + grp; j < end; j += 4) {
    uint2 e = ecol[j];
    float w = __builtin_bit_cast(float, e.y);
    uint4 v = xwb4[(size_t)e.x * 16 + t];
    acc[0] = fmaf(bf16lo(v.x), w, acc[0]);
    acc[1] = fmaf(bf16hi(v.x), w, acc[1]);
    acc[2] = fmaf(bf16lo(v.y), w, acc[2]);
    acc[3] = fmaf(bf16hi(v.y), w, acc[3]);
    acc[4] = fmaf(bf16lo(v.z), w, acc[4]);
    acc[5] = fmaf(bf16hi(v.z), w, acc[5]);
    acc[6] = fmaf(bf16lo(v.w), w, acc[6]);
    acc[7] = fmaf(bf16hi(v.w), w, acc[7]);
  }
#pragma unroll
  for (int k = 0; k < 8; ++k) {
    acc[k] += __shfl_xor(acc[k], 16);
    acc[k] += __shfl_xor(acc[k], 32);
  }
  {
    float wself = wd * wd;
    uint4 v = xwb4[(size_t)d * 16 + t];
    acc[0] = fmaf(bf16lo(v.x), wself, acc[0]);
    acc[1] = fmaf(bf16hi(v.x), wself, acc[1]);
    acc[2] = fmaf(bf16lo(v.y), wself, acc[2]);
    acc[3] = fmaf(bf16hi(v.y), wself, acc[3]);
    acc[4] = fmaf(bf16lo(v.z), wself, acc[4]);
    acc[5] = fmaf(bf16hi(v.z), wself, acc[5]);
    acc[6] = fmaf(bf16lo(v.w), wself, acc[6]);
    acc[7] = fmaf(bf16hi(v.w), wself, acc[7]);
    float4 c0 = *reinterpret_cast<const float4*>(cb + 8 * t);
    float4 c1 = *reinterpret_cast<const float4*>(cb + 8 * t + 4);
    acc[0] += c0.x; acc[1] += c0.y; acc[2] += c0.z; acc[3] += c0.w;
    acc[4] += c1.x; acc[5] += c1.y; acc[6] += c1.z; acc[7] += c1.w;
  }
  float s = acc[0] + acc[1] + acc[2] + acc[3] + acc[4] + acc[5] + acc[6] + acc[7];
#pragma unroll
  for (int m = 1; m < 16; m <<= 1) s += __shfl_xor(s, m);
  float mu = s * (1.0f / HID);
  float sq = 0.0f;
#pragma unroll
  for (int k = 0; k < 8; ++k) {
    acc[k] -= mu;
    sq = fmaf(acc[k], acc[k], sq);
  }
#pragma unroll
  for (int m = 1; m < 16; m <<= 1) sq += __shfl_xor(sq, m);
  float rs = rsqrtf(sq * (1.0f / HID) + LN_EPS);
  float4 g0 = *reinterpret_cast<const float4*>(g + 8 * t);
  float4 g1 = *reinterpret_cast<const float4*>(g + 8 * t + 4);
  float4 b0 = *reinterpret_cast<const float4*>(b + 8 * t);
  float4 b1 = *reinterpret_cast<const float4*>(b + 8 * t + 4);
  float o[8];
  o[0] = acc[0] * rs * g0.x + b0.x;
  o[1] = acc[1] * rs * g0.y + b0.y;
  o[2] = acc[2] * rs * g0.z + b0.z;
  o[3] = acc[3] * rs * g0.w + b0.w;
  o[4] = acc[4] * rs * g1.x + b1.x;
  o[5] = acc[5] * rs * g1.y + b1.y;
  o[6] = acc[6] * rs * g1.z + b1.z;
  o[7] = acc[7] * rs * g1.w + b1.w;
#pragma unroll
  for (int k = 0; k < 8; ++k) o[k] = o[k] >= 0.0f ? o[k] : SLOPE * o[k];

  if (!PROJ) {
    if (grp == 0) {
      float4* op = reinterpret_cast<float4*>(outx + (size_t)d * HID + 8 * t);
      op[0] = make_float4(o[0], o[1], o[2], o[3]);
      op[1] = make_float4(o[4], o[5], o[6], o[7]);
    }
  } else {
    float4 eu0 = *reinterpret_cast<const float4*>(eW + 8 * t);
    float4 eu1 = *reinterpret_cast<const float4*>(eW + 8 * t + 4);
    float4 ef0 = *reinterpret_cast<const float4*>(eW + HID + 8 * t);
    float4 ef1 = *reinterpret_cast<const float4*>(eW + HID + 8 * t + 4);
    float4 ru0 = *reinterpret_cast<const float4*>(rW + 8 * t);
    float4 ru1 = *reinterpret_cast<const float4*>(rW + 8 * t + 4);
    float4 rf0 = *reinterpret_cast<const float4*>(rW + HID + 8 * t);
    float4 rf1 = *reinterpret_cast<const float4*>(rW + HID + 8 * t + 4);
    float pa = o[0]*eu0.x + o[1]*eu0.y + o[2]*eu0.z + o[3]*eu0.w
             + o[4]*eu1.x + o[5]*eu1.y + o[6]*eu1.z + o[7]*eu1.w;
    float pb = o[0]*ef0.x + o[1]*ef0.y + o[2]*ef0.z + o[3]*ef0.w
             + o[4]*ef1.x + o[5]*ef1.y + o[6]*ef1.z + o[7]*ef1.w;
    float pc = o[0]*ru0.x + o[1]*ru0.y + o[2]*ru0.z + o[3]*ru0.w
             + o[4]*ru1.x + o[5]*ru1.y + o[6]*ru1.z + o[7]*ru1.w;
    float pd = o[0]*rf0.x + o[1]*rf0.y + o[2]*rf0.z + o[3]*rf0.w
             + o[4]*rf1.x + o[5]*rf1.y + o[6]*rf1.z + o[7]*rf1.w;
#pragma unroll
    for (int m = 1; m < 16; m <<= 1) {
      pa += __shfl_xor(pa, m);
      pb += __shfl_xor(pb, m);
      pc += __shfl_xor(pc, m);
      pd += __shfl_xor(pd, m);
    }
    if (lane == 0) table[d] = make_float4(pa, pb, pc, pd);
  }
}

// one thread per prediction pair
__global__ void pair_kernel(const int* __restrict__ eu, const int* __restrict__ ef,
                            const float4* __restrict__ table,
                            const float* __restrict__ eb, const float* __restrict__ rb,
                            float* __restrict__ out_exist, float* __restrict__ out_rating,
                            int Ep) {
  int i = blockIdx.x * blockDim.x + threadIdx.x;
  if (i >= Ep) return;
  float4 tu = table[eu[i]];
  float4 tf = table[ef[i]];
  float pe = tu.x + tf.y + eb[0];
  float pr = tu.z + tf.w + rb[0];
  out_exist[i]  = 1.0f / (1.0f + expf(-pe));
  out_rating[i] = 1.0f + 4.0f / (1.0f + expf(-pr));
}

extern "C" void kernel_launch(void* const* d_in, const int* in_sizes, int n_in,
                              void* d_out, int out_size, void* d_ws, size_t ws_size,
                              hipStream_t stream) {
  const float* u_feat = (const float*)d_in[0];
  const float* f_feat = (const float*)d_in[1];
  const int*   ei     = (const int*)d_in[2];
  const int*   eu     = (const int*)d_in[3];
  const int*   ef     = (const int*)d_in[4];
  const float* u_W  = (const float*)d_in[5];
  const float* u_b  = (const float*)d_in[6];
  const float* f_W  = (const float*)d_in[7];
  const float* f_b  = (const float*)d_in[8];
  const float* c1_W = (const float*)d_in[9];
  const float* c1_b = (const float*)d_in[10];
  const float* c2_W = (const float*)d_in[11];
  const float* c2_b = (const float*)d_in[12];
  const float* n1_g = (const float*)d_in[13];
  const float* n1_b = (const float*)d_in[14];
  const float* n2_g = (const float*)d_in[15];
  const float* n2_b = (const float*)d_in[16];
  const float* e_W  = (const float*)d_in[17];
  const float* e_b  = (const float*)d_in[18];
  const float* r_W  = (const float*)d_in[19];
  const float* r_b  = (const float*)d_in[20];

  int n_u = in_sizes[0] / 64;
  int n_f = in_sizes[1] / HID;
  int n   = n_u + n_f;
  int E   = in_sizes[2] / 2;
  int Ep  = in_sizes[3];
  int nbuck = (n + (1 << BSHIFT) - 1) >> BSHIFT;
  int nkey  = nbuck << SUBLOG;

  const int* src = ei;
  const int* dst = ei + E;

  float*        x      = (float*)d_ws;                            // n*HID f32
  unsigned int* xwb    = (unsigned int*)(x + (size_t)n * HID);    // n*HID/2 uint
  float4*       table  = (float4*)(xwb + (size_t)n * (HID / 2));  // n float4
  unsigned int* ebuf   = (unsigned int*)(table + n);              // E uint (packed)
  uint2*        ecol   = (uint2*)(ebuf + E);                      // E uint2 (src, w)
  float*        dinv   = (float*)(ecol + E);                      // n f32
  int*          rowptr = (int*)(dinv + n);                        // n+1 int
  int*          cnt2   = rowptr + n + 1;                          // nkey int
  int*          rowptr2= cnt2 + nkey;                             // nkey+1 int
  int*          blocksum = rowptr2 + nkey + 1;                    // NB_SCAN int
  int*          bcur   = blocksum + NB_SCAN;                      // nkey int
  unsigned int* wt_u   = (unsigned int*)(bcur + nkey);            // 128*32 uint
  unsigned int* wt_f   = wt_u + 128 * 32;                         // 128*64 uint
  unsigned int* wt_c1  = wt_f + 128 * 64;                         // 128*64 uint
  unsigned int* wt_c2  = wt_c1 + 128 * 64;                        // 128*64 uint

  // ---- pre-pack transposed bf16 weights ----
  wt_pack_kernel<<<(128 * 32 + 255) / 256, 256, 0, stream>>>(u_W, wt_u, 64);
  wt_pack_kernel<<<(128 * 64 + 255) / 256, 256, 0, stream>>>(f_W, wt_f, 128);
  wt_pack_kernel<<<(128 * 64 + 255) / 256, 256, 0, stream>>>(c1_W, wt_c1, 128);
  wt_pack_kernel<<<(128 * 64 + 255) / 256, 256, 0, stream>>>(c2_W, wt_c2, 128);

  // ---- bucketed edge sort (by dst>>6) ----
  zero_int_kernel<<<(nkey + 255) / 256, 256, 0, stream>>>(cnt2, nkey);
  hist2_kernel<<<(E + 255) / 256, 256, 0, stream>>>(dst, cnt2, E);
  scan_pass1<<<NB_SCAN, NT_SCAN, 0, stream>>>(cnt2, blocksum, nkey);
  scan_pass2<<<1, NB_SCAN, 0, stream>>>(blocksum);
  scan_pass3<<<NB_SCAN, NT_SCAN, 0, stream>>>(cnt2, blocksum, rowptr2, bcur, nkey);
  bucket_scatter_kernel<<<(E + 255) / 256, 256, 0, stream>>>(src, dst, bcur, ebuf, E);

  // ---- per-node rowptr/dinv, then per-bucket CSR fill ----
  deg_rowptr_kernel<<<nbuck, 256, 0, stream>>>(ebuf, rowptr2, rowptr, dinv, n, nbuck, E);
  fill_bucket_kernel<<<nbuck, 256, 0, stream>>>(ebuf, rowptr2, rowptr, dinv, ecol, n);

  // ---- input embeddings (MFMA, f32 out) ----
  dense_mfma_kernel<64, false><<<(n_u + 31) / 32, 256, 0, stream>>>(
      u_feat, wt_u, u_b, x, nullptr, n_u);
  dense_mfma_kernel<128, false><<<(n_f + 31) / 32, 256, 0, stream>>>(
      f_feat, wt_f, f_b, x + (size_t)n_u * HID, nullptr, n_f);

  // ---- layer 1 ----
  dense_mfma_kernel<128, true><<<(n + 31) / 32, 256, 0, stream>>>(
      x, wt_c1, nullptr, nullptr, (__hip_bfloat16*)xwb, n);
  gather_norm_kernel<false><<<(n + 3) / 4, 256, 0, stream>>>(
      rowptr, ecol, (const uint4*)xwb, dinv, c1_b, n1_g, n1_b,
      nullptr, nullptr, x, nullptr, n);

  // ---- layer 2 (fused prediction-head projection) ----
  dense_mfma_kernel<128, true><<<(n + 31) / 32, 256, 0, stream>>>(
      x, wt_c2, nullptr, nullptr, (__hip_bfloat16*)xwb, n);
  gather_norm_kernel<true><<<(n + 3) / 4, 256, 0, stream>>>(
      rowptr, ecol, (const uint4*)xwb, dinv, c2_b, n2_g, n2_b,
      e_W, r_W, nullptr, table, n);

  // ---- per-pair combine ----
  float* out_exist  = (float*)d_out;
  float* out_rating = out_exist + Ep;
  pair_kernel<<<(Ep + 255) / 256, 256, 0, stream>>>(eu, ef, table, e_b, r_b,
                                                    out_exist, out_rating, Ep);
}

// Round 17
// 361.833 us; speedup vs baseline: 1.6712x; 1.4101x over previous
//
#include <hip/hip_runtime.h>
#include <hip/hip_bf16.h>
#include <math.h>

#define HID 128
#define SLOPE 0.01f
#define LN_EPS 1e-5f
#define NB_SCAN 256
#define NT_SCAN 256
#define BSHIFT 6     // 64 dst nodes per bucket
#define CHUNK 8192   // edges per binning block
#define MAXBUCK 1152

typedef __attribute__((ext_vector_type(8))) short bf16x8;
typedef __attribute__((ext_vector_type(4))) float f32x4;

__device__ __forceinline__ float bf16lo(unsigned int v) {
  unsigned int b = v << 16;
  return __builtin_bit_cast(float, b);
}
__device__ __forceinline__ float bf16hi(unsigned int v) {
  unsigned int b = v & 0xFFFF0000u;
  return __builtin_bit_cast(float, b);
}
__device__ __forceinline__ unsigned int pack_bf16(float lo, float hi) {
  __hip_bfloat16 a = __float2bfloat16(lo);
  __hip_bfloat16 b = __float2bfloat16(hi);
  return (unsigned int)__builtin_bit_cast(unsigned short, a) |
         ((unsigned int)__builtin_bit_cast(unsigned short, b) << 16);
}

// per-chunk LDS histogram over dst buckets -> cntM[b][c]
__global__ __launch_bounds__(256) void hist_chunk_kernel(
    const int* __restrict__ dst, int* __restrict__ cntM,
    int E, int nbuck, int nchunk) {
  __shared__ int hist[MAXBUCK];
  int c = blockIdx.x, tid = threadIdx.x;
  for (int i = tid; i < nbuck; i += 256) hist[i] = 0;
  __syncthreads();
  int beg = c * CHUNK, end = min(beg + CHUNK, E);
  for (int e = beg + tid; e < end; e += 256)
    atomicAdd(&hist[dst[e] >> BSHIFT], 1);
  __syncthreads();
  for (int b = tid; b < nbuck; b += 256)
    cntM[(size_t)b * nchunk + c] = hist[b];
}

// 3-pass exclusive scan over m elements -> scanM[0..m], scanM[m]=total
__global__ void scan_pass1(const int* __restrict__ cnt, int* __restrict__ blocksum, int m) {
  __shared__ int ss[NT_SCAN];
  int K = (m + NB_SCAN * NT_SCAN - 1) / (NB_SCAN * NT_SCAN);
  int t = threadIdx.x, b = blockIdx.x;
  int beg = (b * NT_SCAN + t) * K;
  int end = min(beg + K, m);
  int s = 0;
  for (int i = beg; i < end; ++i) s += cnt[i];
  ss[t] = s;
  __syncthreads();
  for (int off = NT_SCAN / 2; off > 0; off >>= 1) {
    if (t < off) ss[t] += ss[t + off];
    __syncthreads();
  }
  if (t == 0) blocksum[b] = ss[0];
}

__global__ void scan_pass2(int* __restrict__ blocksum) {
  __shared__ int ss[NB_SCAN];
  int t = threadIdx.x;
  ss[t] = blocksum[t];
  __syncthreads();
  for (int off = 1; off < NB_SCAN; off <<= 1) {
    int v = (t >= off) ? ss[t - off] : 0;
    __syncthreads();
    ss[t] += v;
    __syncthreads();
  }
  blocksum[t] = (t == 0) ? 0 : ss[t - 1];
}

__global__ void scan_pass3(const int* __restrict__ cnt, const int* __restrict__ blockoff,
                           int* __restrict__ scanM, int m) {
  __shared__ int ss[NT_SCAN];
  int K = (m + NB_SCAN * NT_SCAN - 1) / (NB_SCAN * NT_SCAN);
  int t = threadIdx.x, b = blockIdx.x;
  int beg = (b * NT_SCAN + t) * K;
  int end = min(beg + K, m);
  int s = 0;
  for (int i = beg; i < end; ++i) s += cnt[i];
  ss[t] = s;
  __syncthreads();
  for (int off = 1; off < NT_SCAN; off <<= 1) {
    int v = (t >= off) ? ss[t - off] : 0;
    __syncthreads();
    ss[t] += v;
    __syncthreads();
  }
  int pre = blockoff[b] + ((t == 0) ? 0 : ss[t - 1]);
  for (int i = beg; i < end; ++i) {
    scanM[i] = pre;
    pre += cnt[i];
    if (i == m - 1) scanM[m] = pre;
  }
}

// deterministic scatter: LDS cursors from scanM, zero global atomics
__global__ __launch_bounds__(256) void scatter_chunk_kernel(
    const int* __restrict__ src, const int* __restrict__ dst,
    const int* __restrict__ scanM, unsigned int* __restrict__ ebuf,
    int E, int nbuck, int nchunk) {
  __shared__ int cur[MAXBUCK];
  int c = blockIdx.x, tid = threadIdx.x;
  for (int b = tid; b < nbuck; b += 256)
    cur[b] = scanM[(size_t)b * nchunk + c];
  __syncthreads();
  int beg = c * CHUNK, end = min(beg + CHUNK, E);
  for (int e = beg + tid; e < end; e += 256) {
    int s = src[e], d = dst[e];
    int pos = atomicAdd(&cur[d >> BSHIFT], 1);
    ebuf[pos] = ((unsigned)s << 6) | ((unsigned)d & 63);
  }
}

// per-bucket: degree count in LDS -> per-node rowptr (bucket base + wave scan),
// dinv.  One block per bucket; bucket range from scanM.
__global__ __launch_bounds__(256) void deg_rowptr_kernel(
    const unsigned int* __restrict__ ebuf, const int* __restrict__ scanM,
    int* __restrict__ rowptr, float* __restrict__ dinv,
    int n, int nbuck, int nchunk, int E) {
  __shared__ int sdeg[64];
  int b = blockIdx.x, tid = threadIdx.x;
  if (tid < 64) sdeg[tid] = 0;
  __syncthreads();
  int beg = scanM[(size_t)b * nchunk], end = scanM[(size_t)(b + 1) * nchunk];
  for (int j = beg + tid; j < end; j += 256) atomicAdd(&sdeg[ebuf[j] & 63], 1);
  __syncthreads();
  if (tid < 64) {
    int deg = sdeg[tid];
    int s = deg;
#pragma unroll
    for (int off = 1; off < 64; off <<= 1) {
      int v = __shfl_up(s, off);
      if (tid >= off) s += v;
    }
    int excl = s - deg;
    int nd = (b << BSHIFT) + tid;
    if (nd < n) {
      rowptr[nd] = beg + excl;
      dinv[nd] = rsqrtf((float)(deg + 1));
    }
    if (b == nbuck - 1 && tid == 0) rowptr[n] = E;
  }
}

// per-bucket CSR fill: LDS cursors, ecol writes in a ~15KB window
__global__ __launch_bounds__(256) void fill_bucket_kernel(
    const unsigned int* __restrict__ ebuf, const int* __restrict__ scanM,
    const int* __restrict__ rowptr, const float* __restrict__ dinv,
    uint2* __restrict__ ecol, int n, int nchunk) {
  __shared__ int scur[64];
  __shared__ int srow[64];
  __shared__ float sdinv[64];
  int b = blockIdx.x, tid = threadIdx.x;
  if (tid < 64) {
    scur[tid] = 0;
    int nd = (b << BSHIFT) + tid;
    srow[tid] = (nd < n) ? rowptr[nd] : 0;
    sdinv[tid] = (nd < n) ? dinv[nd] : 0.0f;
  }
  __syncthreads();
  int beg = scanM[(size_t)b * nchunk], end = scanM[(size_t)(b + 1) * nchunk];
  for (int j = beg + tid; j < end; j += 256) {
    unsigned int v = ebuf[j];
    int ndl = (int)(v & 63);
    int s = (int)(v >> 6);
    int pos = atomicAdd(&scur[ndl], 1);
    float w = dinv[s] * sdinv[ndl];
    ecol[srow[ndl] + pos] = make_uint2((unsigned)s, __builtin_bit_cast(unsigned int, w));
  }
}

// Transpose+pack W[K][128] f32 -> Wt[128][K/2] packed bf16 (k-pairs)
__global__ void wt_pack_kernel(const float* __restrict__ W, unsigned int* __restrict__ Wt,
                               int K) {
  int idx = blockIdx.x * 256 + threadIdx.x;
  int total = 128 * (K / 2);
  if (idx >= total) return;
  int col = idx & 127;
  int k2 = idx >> 7;
  Wt[(size_t)col * (K / 2) + k2] =
      pack_bf16(W[(size_t)(2 * k2) * 128 + col], W[(size_t)(2 * k2 + 1) * 128 + col]);
}

// MFMA dense: out[r][j] = bias[j] + sum_k feat[r][k]*bf16(W[k][j]).
// x split hi/lo bf16 (2 MFMAs).  4 waves/block; wave w: rows base+16*(w&1),
// cols 64*(w>>1)..+64.  No LDS.
template<int K, bool BF16OUT>
__global__ __launch_bounds__(256) void dense_mfma_kernel(
    const float* __restrict__ feat, const unsigned int* __restrict__ Wt,
    const float* __restrict__ bias,
    float* __restrict__ outf, __hip_bfloat16* __restrict__ outb, int nrows) {
  int tid = threadIdx.x;
  int wid = tid >> 6, lane = tid & 63;
  int l15 = lane & 15, lk = lane >> 4;
  int rowbase = blockIdx.x * 32 + 16 * (wid & 1);
  int colbase = 64 * (wid >> 1);

  f32x4 acc0 = {}, acc1 = {}, acc2 = {}, acc3 = {};

  int row = rowbase + l15;
  int rrow = min(row, nrows - 1);
  const float* ap0 = feat + (size_t)rrow * K + lk * 8;

#pragma unroll
  for (int kb = 0; kb < K / 32; ++kb) {
    const float* ap = ap0 + kb * 32;
    float4 a0 = *reinterpret_cast<const float4*>(ap);
    float4 a1 = *reinterpret_cast<const float4*>(ap + 4);
    float af0 = a0.x, af1 = a0.y, af2 = a0.z, af3 = a0.w;
    float af4 = a1.x, af5 = a1.y, af6 = a1.z, af7 = a1.w;
    unsigned int b0 = __builtin_bit_cast(unsigned int, af0);
    unsigned int b1 = __builtin_bit_cast(unsigned int, af1);
    unsigned int b2 = __builtin_bit_cast(unsigned int, af2);
    unsigned int b3 = __builtin_bit_cast(unsigned int, af3);
    unsigned int b4 = __builtin_bit_cast(unsigned int, af4);
    unsigned int b5 = __builtin_bit_cast(unsigned int, af5);
    unsigned int b6 = __builtin_bit_cast(unsigned int, af6);
    unsigned int b7 = __builtin_bit_cast(unsigned int, af7);
    uint4 hv;
    hv.x = (b0 >> 16) | (b1 & 0xFFFF0000u);
    hv.y = (b2 >> 16) | (b3 & 0xFFFF0000u);
    hv.z = (b4 >> 16) | (b5 & 0xFFFF0000u);
    hv.w = (b6 >> 16) | (b7 & 0xFFFF0000u);
    uint4 lv;
    {
      float h0 = __builtin_bit_cast(float, b0 & 0xFFFF0000u);
      float h1 = __builtin_bit_cast(float, b1 & 0xFFFF0000u);
      float h2 = __builtin_bit_cast(float, b2 & 0xFFFF0000u);
      float h3 = __builtin_bit_cast(float, b3 & 0xFFFF0000u);
      float h4 = __builtin_bit_cast(float, b4 & 0xFFFF0000u);
      float h5 = __builtin_bit_cast(float, b5 & 0xFFFF0000u);
      float h6 = __builtin_bit_cast(float, b6 & 0xFFFF0000u);
      float h7 = __builtin_bit_cast(float, b7 & 0xFFFF0000u);
      lv.x = pack_bf16(af0 - h0, af1 - h1);
      lv.y = pack_bf16(af2 - h2, af3 - h3);
      lv.z = pack_bf16(af4 - h4, af5 - h5);
      lv.w = pack_bf16(af6 - h6, af7 - h7);
    }
    bf16x8 ahi = __builtin_bit_cast(bf16x8, hv);
    bf16x8 alo = __builtin_bit_cast(bf16x8, lv);

    const unsigned int* wrow = Wt + (size_t)(colbase + l15) * (K / 2) + kb * 16 + lk * 4;
    bf16x8 bf0 = __builtin_bit_cast(bf16x8, *reinterpret_cast<const uint4*>(wrow));
    bf16x8 bf1 = __builtin_bit_cast(bf16x8, *reinterpret_cast<const uint4*>(wrow + 16 * (K / 2)));
    bf16x8 bf2 = __builtin_bit_cast(bf16x8, *reinterpret_cast<const uint4*>(wrow + 32 * (K / 2)));
    bf16x8 bf3 = __builtin_bit_cast(bf16x8, *reinterpret_cast<const uint4*>(wrow + 48 * (K / 2)));
    acc0 = __builtin_amdgcn_mfma_f32_16x16x32_bf16(ahi, bf0, acc0, 0, 0, 0);
    acc0 = __builtin_amdgcn_mfma_f32_16x16x32_bf16(alo, bf0, acc0, 0, 0, 0);
    acc1 = __builtin_amdgcn_mfma_f32_16x16x32_bf16(ahi, bf1, acc1, 0, 0, 0);
    acc1 = __builtin_amdgcn_mfma_f32_16x16x32_bf16(alo, bf1, acc1, 0, 0, 0);
    acc2 = __builtin_amdgcn_mfma_f32_16x16x32_bf16(ahi, bf2, acc2, 0, 0, 0);
    acc2 = __builtin_amdgcn_mfma_f32_16x16x32_bf16(alo, bf2, acc2, 0, 0, 0);
    acc3 = __builtin_amdgcn_mfma_f32_16x16x32_bf16(ahi, bf3, acc3, 0, 0, 0);
    acc3 = __builtin_amdgcn_mfma_f32_16x16x32_bf16(alo, bf3, acc3, 0, 0, 0);
  }

#pragma unroll
  for (int t = 0; t < 4; ++t) {
    int col = colbase + 16 * t + l15;
    float bv = bias ? bias[col] : 0.0f;
    f32x4 a = (t == 0) ? acc0 : (t == 1) ? acc1 : (t == 2) ? acc2 : acc3;
#pragma unroll
    for (int r = 0; r < 4; ++r) {
      int orow = rowbase + lk * 4 + r;
      if (orow < nrows) {
        float v = a[r] + bv;
        if (BF16OUT) outb[(size_t)orow * HID + col] = __float2bfloat16(v);
        else         outf[(size_t)orow * HID + col] = v;
      }
    }
  }
}

// One wave per dst node; 4 lane-groups of 16, each group one edge/iter:
// uint2 (src, weight) broadcast load + uint4 row load/lane.  (R9-form order.)
template<bool PROJ>
__global__ void gather_norm_kernel(const int* __restrict__ rowptr,
                                   const uint2* __restrict__ ecol,
                                   const uint4* __restrict__ xwb4,
                                   const float* __restrict__ dinv,
                                   const float* __restrict__ cb,
                                   const float* __restrict__ g,
                                   const float* __restrict__ b,
                                   const float* __restrict__ eW,
                                   const float* __restrict__ rW,
                                   float* __restrict__ outx,
                                   float4* __restrict__ table, int n_nodes) {
  int d = blockIdx.x * 4 + (threadIdx.x >> 6);
  if (d >= n_nodes) return;
  int lane = threadIdx.x & 63;
  int grp = lane >> 4;
  int t = lane & 15;

  float acc[8];
#pragma unroll
  for (int k = 0; k < 8; ++k) acc[k] = 0.0f;

  float wd = dinv[d];
  int beg = rowptr[d], end = rowptr[d + 1];
  for (int j = beg + grp; j < end; j += 4) {
    uint2 e = ecol[j];
    float w = __builtin_bit_cast(float, e.y);
    uint4 v = xwb4[(size_t)e.x * 16 + t];
    acc[0] = fmaf(bf16lo(v.x), w, acc[0]);
    acc[1] = fmaf(bf16hi(v.x), w, acc[1]);
    acc[2] = fmaf(bf16lo(v.y), w, acc[2]);
    acc[3] = fmaf(bf16hi(v.y), w, acc[3]);
    acc[4] = fmaf(bf16lo(v.z), w, acc[4]);
    acc[5] = fmaf(bf16hi(v.z), w, acc[5]);
    acc[6] = fmaf(bf16lo(v.w), w, acc[6]);
    acc[7] = fmaf(bf16hi(v.w), w, acc[7]);
  }
#pragma unroll
  for (int k = 0; k < 8; ++k) {
    acc[k] += __shfl_xor(acc[k], 16);
    acc[k] += __shfl_xor(acc[k], 32);
  }
  {
    float wself = wd * wd;
    uint4 v = xwb4[(size_t)d * 16 + t];
    acc[0] = fmaf(bf16lo(v.x), wself, acc[0]);
    acc[1] = fmaf(bf16hi(v.x), wself, acc[1]);
    acc[2] = fmaf(bf16lo(v.y), wself, acc[2]);
    acc[3] = fmaf(bf16hi(v.y), wself, acc[3]);
    acc[4] = fmaf(bf16lo(v.z), wself, acc[4]);
    acc[5] = fmaf(bf16hi(v.z), wself, acc[5]);
    acc[6] = fmaf(bf16lo(v.w), wself, acc[6]);
    acc[7] = fmaf(bf16hi(v.w), wself, acc[7]);
    float4 c0 = *reinterpret_cast<const float4*>(cb + 8 * t);
    float4 c1 = *reinterpret_cast<const float4*>(cb + 8 * t + 4);
    acc[0] += c0.x; acc[1] += c0.y; acc[2] += c0.z; acc[3] += c0.w;
    acc[4] += c1.x; acc[5] += c1.y; acc[6] += c1.z; acc[7] += c1.w;
  }
  float s = acc[0] + acc[1] + acc[2] + acc[3] + acc[4] + acc[5] + acc[6] + acc[7];
#pragma unroll
  for (int m = 1; m < 16; m <<= 1) s += __shfl_xor(s, m);
  float mu = s * (1.0f / HID);
  float sq = 0.0f;
#pragma unroll
  for (int k = 0; k < 8; ++k) {
    acc[k] -= mu;
    sq = fmaf(acc[k], acc[k], sq);
  }
#pragma unroll
  for (int m = 1; m < 16; m <<= 1) sq += __shfl_xor(sq, m);
  float rs = rsqrtf(sq * (1.0f / HID) + LN_EPS);
  float4 g0 = *reinterpret_cast<const float4*>(g + 8 * t);
  float4 g1 = *reinterpret_cast<const float4*>(g + 8 * t + 4);
  float4 b0 = *reinterpret_cast<const float4*>(b + 8 * t);
  float4 b1 = *reinterpret_cast<const float4*>(b + 8 * t + 4);
  float o[8];
  o[0] = acc[0] * rs * g0.x + b0.x;
  o[1] = acc[1] * rs * g0.y + b0.y;
  o[2] = acc[2] * rs * g0.z + b0.z;
  o[3] = acc[3] * rs * g0.w + b0.w;
  o[4] = acc[4] * rs * g1.x + b1.x;
  o[5] = acc[5] * rs * g1.y + b1.y;
  o[6] = acc[6] * rs * g1.z + b1.z;
  o[7] = acc[7] * rs * g1.w + b1.w;
#pragma unroll
  for (int k = 0; k < 8; ++k) o[k] = o[k] >= 0.0f ? o[k] : SLOPE * o[k];

  if (!PROJ) {
    if (grp == 0) {
      float4* op = reinterpret_cast<float4*>(outx + (size_t)d * HID + 8 * t);
      op[0] = make_float4(o[0], o[1], o[2], o[3]);
      op[1] = make_float4(o[4], o[5], o[6], o[7]);
    }
  } else {
    float4 eu0 = *reinterpret_cast<const float4*>(eW + 8 * t);
    float4 eu1 = *reinterpret_cast<const float4*>(eW + 8 * t + 4);
    float4 ef0 = *reinterpret_cast<const float4*>(eW + HID + 8 * t);
    float4 ef1 = *reinterpret_cast<const float4*>(eW + HID + 8 * t + 4);
    float4 ru0 = *reinterpret_cast<const float4*>(rW + 8 * t);
    float4 ru1 = *reinterpret_cast<const float4*>(rW + 8 * t + 4);
    float4 rf0 = *reinterpret_cast<const float4*>(rW + HID + 8 * t);
    float4 rf1 = *reinterpret_cast<const float4*>(rW + HID + 8 * t + 4);
    float pa = o[0]*eu0.x + o[1]*eu0.y + o[2]*eu0.z + o[3]*eu0.w
             + o[4]*eu1.x + o[5]*eu1.y + o[6]*eu1.z + o[7]*eu1.w;
    float pb = o[0]*ef0.x + o[1]*ef0.y + o[2]*ef0.z + o[3]*ef0.w
             + o[4]*ef1.x + o[5]*ef1.y + o[6]*ef1.z + o[7]*ef1.w;
    float pc = o[0]*ru0.x + o[1]*ru0.y + o[2]*ru0.z + o[3]*ru0.w
             + o[4]*ru1.x + o[5]*ru1.y + o[6]*ru1.z + o[7]*ru1.w;
    float pd = o[0]*rf0.x + o[1]*rf0.y + o[2]*rf0.z + o[3]*rf0.w
             + o[4]*rf1.x + o[5]*rf1.y + o[6]*rf1.z + o[7]*rf1.w;
#pragma unroll
    for (int m = 1; m < 16; m <<= 1) {
      pa += __shfl_xor(pa, m);
      pb += __shfl_xor(pb, m);
      pc += __shfl_xor(pc, m);
      pd += __shfl_xor(pd, m);
    }
    if (lane == 0) table[d] = make_float4(pa, pb, pc, pd);
  }
}

// one thread per prediction pair
__global__ void pair_kernel(const int* __restrict__ eu, const int* __restrict__ ef,
                            const float4* __restrict__ table,
                            const float* __restrict__ eb, const float* __restrict__ rb,
                            float* __restrict__ out_exist, float* __restrict__ out_rating,
                            int Ep) {
  int i = blockIdx.x * blockDim.x + threadIdx.x;
  if (i >= Ep) return;
  float4 tu = table[eu[i]];
  float4 tf = table[ef[i]];
  float pe = tu.x + tf.y + eb[0];
  float pr = tu.z + tf.w + rb[0];
  out_exist[i]  = 1.0f / (1.0f + expf(-pe));
  out_rating[i] = 1.0f + 4.0f / (1.0f + expf(-pr));
}

extern "C" void kernel_launch(void* const* d_in, const int* in_sizes, int n_in,
                              void* d_out, int out_size, void* d_ws, size_t ws_size,
                              hipStream_t stream) {
  const float* u_feat = (const float*)d_in[0];
  const float* f_feat = (const float*)d_in[1];
  const int*   ei     = (const int*)d_in[2];
  const int*   eu     = (const int*)d_in[3];
  const int*   ef     = (const int*)d_in[4];
  const float* u_W  = (const float*)d_in[5];
  const float* u_b  = (const float*)d_in[6];
  const float* f_W  = (const float*)d_in[7];
  const float* f_b  = (const float*)d_in[8];
  const float* c1_W = (const float*)d_in[9];
  const float* c1_b = (const float*)d_in[10];
  const float* c2_W = (const float*)d_in[11];
  const float* c2_b = (const float*)d_in[12];
  const float* n1_g = (const float*)d_in[13];
  const float* n1_b = (const float*)d_in[14];
  const float* n2_g = (const float*)d_in[15];
  const float* n2_b = (const float*)d_in[16];
  const float* e_W  = (const float*)d_in[17];
  const float* e_b  = (const float*)d_in[18];
  const float* r_W  = (const float*)d_in[19];
  const float* r_b  = (const float*)d_in[20];

  int n_u = in_sizes[0] / 64;
  int n_f = in_sizes[1] / HID;
  int n   = n_u + n_f;
  int E   = in_sizes[2] / 2;
  int Ep  = in_sizes[3];
  int nbuck  = (n + (1 << BSHIFT) - 1) >> BSHIFT;
  int nchunk = (E + CHUNK - 1) / CHUNK;
  int m      = nbuck * nchunk;

  const int* src = ei;
  const int* dst = ei + E;

  float*        x      = (float*)d_ws;                            // n*HID f32
  unsigned int* xwb    = (unsigned int*)(x + (size_t)n * HID);    // n*HID/2 uint
  float4*       table  = (float4*)(xwb + (size_t)n * (HID / 2));  // n float4
  unsigned int* ebuf   = (unsigned int*)(table + n);              // E uint (packed)
  uint2*        ecol   = (uint2*)(ebuf + E);                      // E uint2 (src, w)
  float*        dinv   = (float*)(ecol + E);                      // n f32
  int*          rowptr = (int*)(dinv + n);                        // n+1 int
  int*          cntM   = rowptr + n + 1;                          // m int
  int*          scanM  = cntM + m;                                // m+1 int
  int*          blocksum = scanM + m + 1;                         // NB_SCAN int
  unsigned int* wt_u   = (unsigned int*)(blocksum + NB_SCAN);     // 128*32 uint
  unsigned int* wt_f   = wt_u + 128 * 32;                         // 128*64 uint
  unsigned int* wt_c1  = wt_f + 128 * 64;                         // 128*64 uint
  unsigned int* wt_c2  = wt_c1 + 128 * 64;                        // 128*64 uint

  // ---- pre-pack transposed bf16 weights ----
  wt_pack_kernel<<<(128 * 32 + 255) / 256, 256, 0, stream>>>(u_W, wt_u, 64);
  wt_pack_kernel<<<(128 * 64 + 255) / 256, 256, 0, stream>>>(f_W, wt_f, 128);
  wt_pack_kernel<<<(128 * 64 + 255) / 256, 256, 0, stream>>>(c1_W, wt_c1, 128);
  wt_pack_kernel<<<(128 * 64 + 255) / 256, 256, 0, stream>>>(c2_W, wt_c2, 128);

  // ---- deterministic radix binning of edges by dst bucket ----
  hist_chunk_kernel<<<nchunk, 256, 0, stream>>>(dst, cntM, E, nbuck, nchunk);
  scan_pass1<<<NB_SCAN, NT_SCAN, 0, stream>>>(cntM, blocksum, m);
  scan_pass2<<<1, NB_SCAN, 0, stream>>>(blocksum);
  scan_pass3<<<NB_SCAN, NT_SCAN, 0, stream>>>(cntM, blocksum, scanM, m);
  scatter_chunk_kernel<<<nchunk, 256, 0, stream>>>(src, dst, scanM, ebuf, E, nbuck, nchunk);

  // ---- per-node rowptr/dinv, then per-bucket CSR fill ----
  deg_rowptr_kernel<<<nbuck, 256, 0, stream>>>(ebuf, scanM, rowptr, dinv,
                                               n, nbuck, nchunk, E);
  fill_bucket_kernel<<<nbuck, 256, 0, stream>>>(ebuf, scanM, rowptr, dinv, ecol,
                                                n, nchunk);

  // ---- input embeddings (MFMA, f32 out) ----
  dense_mfma_kernel<64, false><<<(n_u + 31) / 32, 256, 0, stream>>>(
      u_feat, wt_u, u_b, x, nullptr, n_u);
  dense_mfma_kernel<128, false><<<(n_f + 31) / 32, 256, 0, stream>>>(
      f_feat, wt_f, f_b, x + (size_t)n_u * HID, nullptr, n_f);

  // ---- layer 1 ----
  dense_mfma_kernel<128, true><<<(n + 31) / 32, 256, 0, stream>>>(
      x, wt_c1, nullptr, nullptr, (__hip_bfloat16*)xwb, n);
  gather_norm_kernel<false><<<(n + 3) / 4, 256, 0, stream>>>(
      rowptr, ecol, (const uint4*)xwb, dinv, c1_b, n1_g, n1_b,
      nullptr, nullptr, x, nullptr, n);

  // ---- layer 2 (fused prediction-head projection) ----
  dense_mfma_kernel<128, true><<<(n + 31) / 32, 256, 0, stream>>>(
      x, wt_c2, nullptr, nullptr, (__hip_bfloat16*)xwb, n);
  gather_norm_kernel<true><<<(n + 3) / 4, 256, 0, stream>>>(
      rowptr, ecol, (const uint4*)xwb, dinv, c2_b, n2_g, n2_b,
      e_W, r_W, nullptr, table, n);

  // ---- per-pair combine ----
  float* out_exist  = (float*)d_out;
  float* out_rating = out_exist + Ep;
  pair_kernel<<<(Ep + 255) / 256, 256, 0, stream>>>(eu, ef, table, e_b, r_b,
                                                    out_exist, out_rating, Ep);
}

// Round 18
// 325.006 us; speedup vs baseline: 1.8606x; 1.1133x over previous
//
#include <hip/hip_runtime.h>
#include <hip/hip_bf16.h>
#include <math.h>

#define HID 128
#define SLOPE 0.01f
#define LN_EPS 1e-5f
#define NB_SCAN 256
#define NT_SCAN 256
#define BSHIFT 6     // 64 dst nodes per bucket
#define CHUNK 8192   // edges per binning block
#define MAXBUCK 1152

typedef __attribute__((ext_vector_type(8))) short bf16x8;
typedef __attribute__((ext_vector_type(4))) float f32x4;

__device__ __forceinline__ float bf16lo(unsigned int v) {
  unsigned int b = v << 16;
  return __builtin_bit_cast(float, b);
}
__device__ __forceinline__ float bf16hi(unsigned int v) {
  unsigned int b = v & 0xFFFF0000u;
  return __builtin_bit_cast(float, b);
}
__device__ __forceinline__ unsigned int pack_bf16(float lo, float hi) {
  __hip_bfloat16 a = __float2bfloat16(lo);
  __hip_bfloat16 b = __float2bfloat16(hi);
  return (unsigned int)__builtin_bit_cast(unsigned short, a) |
         ((unsigned int)__builtin_bit_cast(unsigned short, b) << 16);
}

// per-chunk LDS histogram over dst buckets -> cntM[b][c]
__global__ __launch_bounds__(256) void hist_chunk_kernel(
    const int* __restrict__ dst, int* __restrict__ cntM,
    int E, int nbuck, int nchunk) {
  __shared__ int hist[MAXBUCK];
  int c = blockIdx.x, tid = threadIdx.x;
  for (int i = tid; i < nbuck; i += 256) hist[i] = 0;
  __syncthreads();
  int beg = c * CHUNK, end = min(beg + CHUNK, E);
  for (int e = beg + tid; e < end; e += 256)
    atomicAdd(&hist[dst[e] >> BSHIFT], 1);
  __syncthreads();
  for (int b = tid; b < nbuck; b += 256)
    cntM[(size_t)b * nchunk + c] = hist[b];
}

// 3-pass exclusive scan over m elements -> scanM[0..m], scanM[m]=total
__global__ void scan_pass1(const int* __restrict__ cnt, int* __restrict__ blocksum, int m) {
  __shared__ int ss[NT_SCAN];
  int K = (m + NB_SCAN * NT_SCAN - 1) / (NB_SCAN * NT_SCAN);
  int t = threadIdx.x, b = blockIdx.x;
  int beg = (b * NT_SCAN + t) * K;
  int end = min(beg + K, m);
  int s = 0;
  for (int i = beg; i < end; ++i) s += cnt[i];
  ss[t] = s;
  __syncthreads();
  for (int off = NT_SCAN / 2; off > 0; off >>= 1) {
    if (t < off) ss[t] += ss[t + off];
    __syncthreads();
  }
  if (t == 0) blocksum[b] = ss[0];
}

__global__ void scan_pass2(int* __restrict__ blocksum) {
  __shared__ int ss[NB_SCAN];
  int t = threadIdx.x;
  ss[t] = blocksum[t];
  __syncthreads();
  for (int off = 1; off < NB_SCAN; off <<= 1) {
    int v = (t >= off) ? ss[t - off] : 0;
    __syncthreads();
    ss[t] += v;
    __syncthreads();
  }
  blocksum[t] = (t == 0) ? 0 : ss[t - 1];
}

__global__ void scan_pass3(const int* __restrict__ cnt, const int* __restrict__ blockoff,
                           int* __restrict__ scanM, int m) {
  __shared__ int ss[NT_SCAN];
  int K = (m + NB_SCAN * NT_SCAN - 1) / (NB_SCAN * NT_SCAN);
  int t = threadIdx.x, b = blockIdx.x;
  int beg = (b * NT_SCAN + t) * K;
  int end = min(beg + K, m);
  int s = 0;
  for (int i = beg; i < end; ++i) s += cnt[i];
  ss[t] = s;
  __syncthreads();
  for (int off = 1; off < NT_SCAN; off <<= 1) {
    int v = (t >= off) ? ss[t - off] : 0;
    __syncthreads();
    ss[t] += v;
    __syncthreads();
  }
  int pre = blockoff[b] + ((t == 0) ? 0 : ss[t - 1]);
  for (int i = beg; i < end; ++i) {
    scanM[i] = pre;
    pre += cnt[i];
    if (i == m - 1) scanM[m] = pre;
  }
}

// deterministic scatter: LDS cursors from scanM, zero global atomics
__global__ __launch_bounds__(256) void scatter_chunk_kernel(
    const int* __restrict__ src, const int* __restrict__ dst,
    const int* __restrict__ scanM, unsigned int* __restrict__ ebuf,
    int E, int nbuck, int nchunk) {
  __shared__ int cur[MAXBUCK];
  int c = blockIdx.x, tid = threadIdx.x;
  for (int b = tid; b < nbuck; b += 256)
    cur[b] = scanM[(size_t)b * nchunk + c];
  __syncthreads();
  int beg = c * CHUNK, end = min(beg + CHUNK, E);
  for (int e = beg + tid; e < end; e += 256) {
    int s = src[e], d = dst[e];
    int pos = atomicAdd(&cur[d >> BSHIFT], 1);
    ebuf[pos] = ((unsigned)s << 6) | ((unsigned)d & 63);
  }
}

// per-bucket: degree count in LDS -> per-node rowptr (bucket base + wave scan),
// dinv.  One block per bucket; bucket range from scanM.
__global__ __launch_bounds__(256) void deg_rowptr_kernel(
    const unsigned int* __restrict__ ebuf, const int* __restrict__ scanM,
    int* __restrict__ rowptr, float* __restrict__ dinv,
    int n, int nbuck, int nchunk, int E) {
  __shared__ int sdeg[64];
  int b = blockIdx.x, tid = threadIdx.x;
  if (tid < 64) sdeg[tid] = 0;
  __syncthreads();
  int beg = scanM[(size_t)b * nchunk], end = scanM[(size_t)(b + 1) * nchunk];
  for (int j = beg + tid; j < end; j += 256) atomicAdd(&sdeg[ebuf[j] & 63], 1);
  __syncthreads();
  if (tid < 64) {
    int deg = sdeg[tid];
    int s = deg;
#pragma unroll
    for (int off = 1; off < 64; off <<= 1) {
      int v = __shfl_up(s, off);
      if (tid >= off) s += v;
    }
    int excl = s - deg;
    int nd = (b << BSHIFT) + tid;
    if (nd < n) {
      rowptr[nd] = beg + excl;
      dinv[nd] = rsqrtf((float)(deg + 1));
    }
    if (b == nbuck - 1 && tid == 0) rowptr[n] = E;
  }
}

// per-bucket CSR fill: LDS cursors, ecol writes in a ~15KB window
__global__ __launch_bounds__(256) void fill_bucket_kernel(
    const unsigned int* __restrict__ ebuf, const int* __restrict__ scanM,
    const int* __restrict__ rowptr, const float* __restrict__ dinv,
    uint2* __restrict__ ecol, int n, int nchunk) {
  __shared__ int scur[64];
  __shared__ int srow[64];
  __shared__ float sdinv[64];
  int b = blockIdx.x, tid = threadIdx.x;
  if (tid < 64) {
    scur[tid] = 0;
    int nd = (b << BSHIFT) + tid;
    srow[tid] = (nd < n) ? rowptr[nd] : 0;
    sdinv[tid] = (nd < n) ? dinv[nd] : 0.0f;
  }
  __syncthreads();
  int beg = scanM[(size_t)b * nchunk], end = scanM[(size_t)(b + 1) * nchunk];
  for (int j = beg + tid; j < end; j += 256) {
    unsigned int v = ebuf[j];
    int ndl = (int)(v & 63);
    int s = (int)(v >> 6);
    int pos = atomicAdd(&scur[ndl], 1);
    float w = dinv[s] * sdinv[ndl];
    ecol[srow[ndl] + pos] = make_uint2((unsigned)s, __builtin_bit_cast(unsigned int, w));
  }
}

// Composed weight: Wt[col][k2] = pack_bf16( (A@B)[2k2][col], (A@B)[2k2+1][col] )
// A: K x 128 (f32), B: 128 x 128 (f32)
__global__ void compose_pack_kernel(const float* __restrict__ A, const float* __restrict__ B,
                                    unsigned int* __restrict__ Wt, int K) {
  int idx = blockIdx.x * 256 + threadIdx.x;
  int total = 128 * (K / 2);
  if (idx >= total) return;
  int col = idx & 127;
  int k2 = idx >> 7;
  float s0 = 0.0f, s1 = 0.0f;
  const float* a0 = A + (size_t)(2 * k2) * 128;
  const float* a1 = a0 + 128;
  for (int m = 0; m < 128; ++m) {
    float bm = B[(size_t)m * 128 + col];
    s0 = fmaf(a0[m], bm, s0);
    s1 = fmaf(a1[m], bm, s1);
  }
  Wt[(size_t)col * (K / 2) + k2] = pack_bf16(s0, s1);
}

// bias_comp[j] = sum_m bvec[m] * B[m][j]
__global__ void bias_comp_kernel(const float* __restrict__ bvec, const float* __restrict__ B,
                                 float* __restrict__ out) {
  int j = threadIdx.x;
  float s = 0.0f;
  for (int m = 0; m < 128; ++m) s = fmaf(bvec[m], B[(size_t)m * 128 + j], s);
  out[j] = s;
}

// Transpose+pack W[K][128] f32 -> Wt[128][K/2] packed bf16 (k-pairs)
__global__ void wt_pack_kernel(const float* __restrict__ W, unsigned int* __restrict__ Wt,
                               int K) {
  int idx = blockIdx.x * 256 + threadIdx.x;
  int total = 128 * (K / 2);
  if (idx >= total) return;
  int col = idx & 127;
  int k2 = idx >> 7;
  Wt[(size_t)col * (K / 2) + k2] =
      pack_bf16(W[(size_t)(2 * k2) * 128 + col], W[(size_t)(2 * k2 + 1) * 128 + col]);
}

// MFMA dense: out[r][j] = bias[j] + sum_k feat[r][k]*bf16(W[k][j]).
// x split hi/lo bf16 (2 MFMAs).  4 waves/block; wave w: rows base+16*(w&1),
// cols 64*(w>>1)..+64.  No LDS.
template<int K, bool BF16OUT>
__global__ __launch_bounds__(256) void dense_mfma_kernel(
    const float* __restrict__ feat, const unsigned int* __restrict__ Wt,
    const float* __restrict__ bias,
    float* __restrict__ outf, __hip_bfloat16* __restrict__ outb, int nrows) {
  int tid = threadIdx.x;
  int wid = tid >> 6, lane = tid & 63;
  int l15 = lane & 15, lk = lane >> 4;
  int rowbase = blockIdx.x * 32 + 16 * (wid & 1);
  int colbase = 64 * (wid >> 1);

  f32x4 acc0 = {}, acc1 = {}, acc2 = {}, acc3 = {};

  int row = rowbase + l15;
  int rrow = min(row, nrows - 1);
  const float* ap0 = feat + (size_t)rrow * K + lk * 8;

#pragma unroll
  for (int kb = 0; kb < K / 32; ++kb) {
    const float* ap = ap0 + kb * 32;
    float4 a0 = *reinterpret_cast<const float4*>(ap);
    float4 a1 = *reinterpret_cast<const float4*>(ap + 4);
    float af0 = a0.x, af1 = a0.y, af2 = a0.z, af3 = a0.w;
    float af4 = a1.x, af5 = a1.y, af6 = a1.z, af7 = a1.w;
    unsigned int b0 = __builtin_bit_cast(unsigned int, af0);
    unsigned int b1 = __builtin_bit_cast(unsigned int, af1);
    unsigned int b2 = __builtin_bit_cast(unsigned int, af2);
    unsigned int b3 = __builtin_bit_cast(unsigned int, af3);
    unsigned int b4 = __builtin_bit_cast(unsigned int, af4);
    unsigned int b5 = __builtin_bit_cast(unsigned int, af5);
    unsigned int b6 = __builtin_bit_cast(unsigned int, af6);
    unsigned int b7 = __builtin_bit_cast(unsigned int, af7);
    uint4 hv;
    hv.x = (b0 >> 16) | (b1 & 0xFFFF0000u);
    hv.y = (b2 >> 16) | (b3 & 0xFFFF0000u);
    hv.z = (b4 >> 16) | (b5 & 0xFFFF0000u);
    hv.w = (b6 >> 16) | (b7 & 0xFFFF0000u);
    uint4 lv;
    {
      float h0 = __builtin_bit_cast(float, b0 & 0xFFFF0000u);
      float h1 = __builtin_bit_cast(float, b1 & 0xFFFF0000u);
      float h2 = __builtin_bit_cast(float, b2 & 0xFFFF0000u);
      float h3 = __builtin_bit_cast(float, b3 & 0xFFFF0000u);
      float h4 = __builtin_bit_cast(float, b4 & 0xFFFF0000u);
      float h5 = __builtin_bit_cast(float, b5 & 0xFFFF0000u);
      float h6 = __builtin_bit_cast(float, b6 & 0xFFFF0000u);
      float h7 = __builtin_bit_cast(float, b7 & 0xFFFF0000u);
      lv.x = pack_bf16(af0 - h0, af1 - h1);
      lv.y = pack_bf16(af2 - h2, af3 - h3);
      lv.z = pack_bf16(af4 - h4, af5 - h5);
      lv.w = pack_bf16(af6 - h6, af7 - h7);
    }
    bf16x8 ahi = __builtin_bit_cast(bf16x8, hv);
    bf16x8 alo = __builtin_bit_cast(bf16x8, lv);

    const unsigned int* wrow = Wt + (size_t)(colbase + l15) * (K / 2) + kb * 16 + lk * 4;
    bf16x8 bf0 = __builtin_bit_cast(bf16x8, *reinterpret_cast<const uint4*>(wrow));
    bf16x8 bf1 = __builtin_bit_cast(bf16x8, *reinterpret_cast<const uint4*>(wrow + 16 * (K / 2)));
    bf16x8 bf2 = __builtin_bit_cast(bf16x8, *reinterpret_cast<const uint4*>(wrow + 32 * (K / 2)));
    bf16x8 bf3 = __builtin_bit_cast(bf16x8, *reinterpret_cast<const uint4*>(wrow + 48 * (K / 2)));
    acc0 = __builtin_amdgcn_mfma_f32_16x16x32_bf16(ahi, bf0, acc0, 0, 0, 0);
    acc0 = __builtin_amdgcn_mfma_f32_16x16x32_bf16(alo, bf0, acc0, 0, 0, 0);
    acc1 = __builtin_amdgcn_mfma_f32_16x16x32_bf16(ahi, bf1, acc1, 0, 0, 0);
    acc1 = __builtin_amdgcn_mfma_f32_16x16x32_bf16(alo, bf1, acc1, 0, 0, 0);
    acc2 = __builtin_amdgcn_mfma_f32_16x16x32_bf16(ahi, bf2, acc2, 0, 0, 0);
    acc2 = __builtin_amdgcn_mfma_f32_16x16x32_bf16(alo, bf2, acc2, 0, 0, 0);
    acc3 = __builtin_amdgcn_mfma_f32_16x16x32_bf16(ahi, bf3, acc3, 0, 0, 0);
    acc3 = __builtin_amdgcn_mfma_f32_16x16x32_bf16(alo, bf3, acc3, 0, 0, 0);
  }

#pragma unroll
  for (int t = 0; t < 4; ++t) {
    int col = colbase + 16 * t + l15;
    float bv = bias ? bias[col] : 0.0f;
    f32x4 a = (t == 0) ? acc0 : (t == 1) ? acc1 : (t == 2) ? acc2 : acc3;
#pragma unroll
    for (int r = 0; r < 4; ++r) {
      int orow = rowbase + lk * 4 + r;
      if (orow < nrows) {
        float v = a[r] + bv;
        if (BF16OUT) outb[(size_t)orow * HID + col] = __float2bfloat16(v);
        else         outf[(size_t)orow * HID + col] = v;
      }
    }
  }
}

// One wave per dst node; 4 lane-groups of 16; unroll x2 (edges j, j+4 per iter,
// same per-group summation order as stride-4 => bit-exact vs R17).
template<bool PROJ>
__global__ void gather_norm_kernel(const int* __restrict__ rowptr,
                                   const uint2* __restrict__ ecol,
                                   const uint4* __restrict__ xwb4,
                                   const float* __restrict__ dinv,
                                   const float* __restrict__ cb,
                                   const float* __restrict__ g,
                                   const float* __restrict__ b,
                                   const float* __restrict__ eW,
                                   const float* __restrict__ rW,
                                   float* __restrict__ outx,
                                   float4* __restrict__ table, int n_nodes) {
  int d = blockIdx.x * 4 + (threadIdx.x >> 6);
  if (d >= n_nodes) return;
  int lane = threadIdx.x & 63;
  int grp = lane >> 4;
  int t = lane & 15;

  float acc[8];
#pragma unroll
  for (int k = 0; k < 8; ++k) acc[k] = 0.0f;

  float wd = dinv[d];
  int beg = rowptr[d], end = rowptr[d + 1];
  int j = beg + grp;
  for (; j + 4 < end; j += 8) {
    uint2 e0 = ecol[j];
    uint2 e1 = ecol[j + 4];
    uint4 v0 = xwb4[(size_t)e0.x * 16 + t];
    uint4 v1 = xwb4[(size_t)e1.x * 16 + t];
    float w0 = __builtin_bit_cast(float, e0.y);
    float w1 = __builtin_bit_cast(float, e1.y);
    acc[0] = fmaf(bf16lo(v0.x), w0, acc[0]);
    acc[1] = fmaf(bf16hi(v0.x), w0, acc[1]);
    acc[2] = fmaf(bf16lo(v0.y), w0, acc[2]);
    acc[3] = fmaf(bf16hi(v0.y), w0, acc[3]);
    acc[4] = fmaf(bf16lo(v0.z), w0, acc[4]);
    acc[5] = fmaf(bf16hi(v0.z), w0, acc[5]);
    acc[6] = fmaf(bf16lo(v0.w), w0, acc[6]);
    acc[7] = fmaf(bf16hi(v0.w), w0, acc[7]);
    acc[0] = fmaf(bf16lo(v1.x), w1, acc[0]);
    acc[1] = fmaf(bf16hi(v1.x), w1, acc[1]);
    acc[2] = fmaf(bf16lo(v1.y), w1, acc[2]);
    acc[3] = fmaf(bf16hi(v1.y), w1, acc[3]);
    acc[4] = fmaf(bf16lo(v1.z), w1, acc[4]);
    acc[5] = fmaf(bf16hi(v1.z), w1, acc[5]);
    acc[6] = fmaf(bf16lo(v1.w), w1, acc[6]);
    acc[7] = fmaf(bf16hi(v1.w), w1, acc[7]);
  }
  if (j < end) {
    uint2 e0 = ecol[j];
    uint4 v0 = xwb4[(size_t)e0.x * 16 + t];
    float w0 = __builtin_bit_cast(float, e0.y);
    acc[0] = fmaf(bf16lo(v0.x), w0, acc[0]);
    acc[1] = fmaf(bf16hi(v0.x), w0, acc[1]);
    acc[2] = fmaf(bf16lo(v0.y), w0, acc[2]);
    acc[3] = fmaf(bf16hi(v0.y), w0, acc[3]);
    acc[4] = fmaf(bf16lo(v0.z), w0, acc[4]);
    acc[5] = fmaf(bf16hi(v0.z), w0, acc[5]);
    acc[6] = fmaf(bf16lo(v0.w), w0, acc[6]);
    acc[7] = fmaf(bf16hi(v0.w), w0, acc[7]);
  }
#pragma unroll
  for (int k = 0; k < 8; ++k) {
    acc[k] += __shfl_xor(acc[k], 16);
    acc[k] += __shfl_xor(acc[k], 32);
  }
  {
    float wself = wd * wd;
    uint4 v = xwb4[(size_t)d * 16 + t];
    acc[0] = fmaf(bf16lo(v.x), wself, acc[0]);
    acc[1] = fmaf(bf16hi(v.x), wself, acc[1]);
    acc[2] = fmaf(bf16lo(v.y), wself, acc[2]);
    acc[3] = fmaf(bf16hi(v.y), wself, acc[3]);
    acc[4] = fmaf(bf16lo(v.z), wself, acc[4]);
    acc[5] = fmaf(bf16hi(v.z), wself, acc[5]);
    acc[6] = fmaf(bf16lo(v.w), wself, acc[6]);
    acc[7] = fmaf(bf16hi(v.w), wself, acc[7]);
    float4 c0 = *reinterpret_cast<const float4*>(cb + 8 * t);
    float4 c1 = *reinterpret_cast<const float4*>(cb + 8 * t + 4);
    acc[0] += c0.x; acc[1] += c0.y; acc[2] += c0.z; acc[3] += c0.w;
    acc[4] += c1.x; acc[5] += c1.y; acc[6] += c1.z; acc[7] += c1.w;
  }
  float s = acc[0] + acc[1] + acc[2] + acc[3] + acc[4] + acc[5] + acc[6] + acc[7];
#pragma unroll
  for (int m = 1; m < 16; m <<= 1) s += __shfl_xor(s, m);
  float mu = s * (1.0f / HID);
  float sq = 0.0f;
#pragma unroll
  for (int k = 0; k < 8; ++k) {
    acc[k] -= mu;
    sq = fmaf(acc[k], acc[k], sq);
  }
#pragma unroll
  for (int m = 1; m < 16; m <<= 1) sq += __shfl_xor(sq, m);
  float rs = rsqrtf(sq * (1.0f / HID) + LN_EPS);
  float4 g0 = *reinterpret_cast<const float4*>(g + 8 * t);
  float4 g1 = *reinterpret_cast<const float4*>(g + 8 * t + 4);
  float4 b0 = *reinterpret_cast<const float4*>(b + 8 * t);
  float4 b1 = *reinterpret_cast<const float4*>(b + 8 * t + 4);
  float o[8];
  o[0] = acc[0] * rs * g0.x + b0.x;
  o[1] = acc[1] * rs * g0.y + b0.y;
  o[2] = acc[2] * rs * g0.z + b0.z;
  o[3] = acc[3] * rs * g0.w + b0.w;
  o[4] = acc[4] * rs * g1.x + b1.x;
  o[5] = acc[5] * rs * g1.y + b1.y;
  o[6] = acc[6] * rs * g1.z + b1.z;
  o[7] = acc[7] * rs * g1.w + b1.w;
#pragma unroll
  for (int k = 0; k < 8; ++k) o[k] = o[k] >= 0.0f ? o[k] : SLOPE * o[k];

  if (!PROJ) {
    if (grp == 0) {
      float4* op = reinterpret_cast<float4*>(outx + (size_t)d * HID + 8 * t);
      op[0] = make_float4(o[0], o[1], o[2], o[3]);
      op[1] = make_float4(o[4], o[5], o[6], o[7]);
    }
  } else {
    float4 eu0 = *reinterpret_cast<const float4*>(eW + 8 * t);
    float4 eu1 = *reinterpret_cast<const float4*>(eW + 8 * t + 4);
    float4 ef0 = *reinterpret_cast<const float4*>(eW + HID + 8 * t);
    float4 ef1 = *reinterpret_cast<const float4*>(eW + HID + 8 * t + 4);
    float4 ru0 = *reinterpret_cast<const float4*>(rW + 8 * t);
    float4 ru1 = *reinterpret_cast<const float4*>(rW + 8 * t + 4);
    float4 rf0 = *reinterpret_cast<const float4*>(rW + HID + 8 * t);
    float4 rf1 = *reinterpret_cast<const float4*>(rW + HID + 8 * t + 4);
    float pa = o[0]*eu0.x + o[1]*eu0.y + o[2]*eu0.z + o[3]*eu0.w
             + o[4]*eu1.x + o[5]*eu1.y + o[6]*eu1.z + o[7]*eu1.w;
    float pb = o[0]*ef0.x + o[1]*ef0.y + o[2]*ef0.z + o[3]*ef0.w
             + o[4]*ef1.x + o[5]*ef1.y + o[6]*ef1.z + o[7]*ef1.w;
    float pc = o[0]*ru0.x + o[1]*ru0.y + o[2]*ru0.z + o[3]*ru0.w
             + o[4]*ru1.x + o[5]*ru1.y + o[6]*ru1.z + o[7]*ru1.w;
    float pd = o[0]*rf0.x + o[1]*rf0.y + o[2]*rf0.z + o[3]*rf0.w
             + o[4]*rf1.x + o[5]*rf1.y + o[6]*rf1.z + o[7]*rf1.w;
#pragma unroll
    for (int m = 1; m < 16; m <<= 1) {
      pa += __shfl_xor(pa, m);
      pb += __shfl_xor(pb, m);
      pc += __shfl_xor(pc, m);
      pd += __shfl_xor(pd, m);
    }
    if (lane == 0) table[d] = make_float4(pa, pb, pc, pd);
  }
}

// one thread per prediction pair
__global__ void pair_kernel(const int* __restrict__ eu, const int* __restrict__ ef,
                            const float4* __restrict__ table,
                            const float* __restrict__ eb, const float* __restrict__ rb,
                            float* __restrict__ out_exist, float* __restrict__ out_rating,
                            int Ep) {
  int i = blockIdx.x * blockDim.x + threadIdx.x;
  if (i >= Ep) return;
  float4 tu = table[eu[i]];
  float4 tf = table[ef[i]];
  float pe = tu.x + tf.y + eb[0];
  float pr = tu.z + tf.w + rb[0];
  out_exist[i]  = 1.0f / (1.0f + expf(-pe));
  out_rating[i] = 1.0f + 4.0f / (1.0f + expf(-pr));
}

extern "C" void kernel_launch(void* const* d_in, const int* in_sizes, int n_in,
                              void* d_out, int out_size, void* d_ws, size_t ws_size,
                              hipStream_t stream) {
  const float* u_feat = (const float*)d_in[0];
  const float* f_feat = (const float*)d_in[1];
  const int*   ei     = (const int*)d_in[2];
  const int*   eu     = (const int*)d_in[3];
  const int*   ef     = (const int*)d_in[4];
  const float* u_W  = (const float*)d_in[5];
  const float* u_b  = (const float*)d_in[6];
  const float* f_W  = (const float*)d_in[7];
  const float* f_b  = (const float*)d_in[8];
  const float* c1_W = (const float*)d_in[9];
  const float* c1_b = (const float*)d_in[10];
  const float* c2_W = (const float*)d_in[11];
  const float* c2_b = (const float*)d_in[12];
  const float* n1_g = (const float*)d_in[13];
  const float* n1_b = (const float*)d_in[14];
  const float* n2_g = (const float*)d_in[15];
  const float* n2_b = (const float*)d_in[16];
  const float* e_W  = (const float*)d_in[17];
  const float* e_b  = (const float*)d_in[18];
  const float* r_W  = (const float*)d_in[19];
  const float* r_b  = (const float*)d_in[20];

  int n_u = in_sizes[0] / 64;
  int n_f = in_sizes[1] / HID;
  int n   = n_u + n_f;
  int E   = in_sizes[2] / 2;
  int Ep  = in_sizes[3];
  int nbuck  = (n + (1 << BSHIFT) - 1) >> BSHIFT;
  int nchunk = (E + CHUNK - 1) / CHUNK;
  int m      = nbuck * nchunk;

  const int* src = ei;
  const int* dst = ei + E;

  float*        x      = (float*)d_ws;                            // n*HID f32
  unsigned int* xwb    = (unsigned int*)(x + (size_t)n * HID);    // n*HID/2 uint
  float4*       table  = (float4*)(xwb + (size_t)n * (HID / 2));  // n float4
  unsigned int* ebuf   = (unsigned int*)(table + n);              // E uint (packed)
  uint2*        ecol   = (uint2*)(ebuf + E);                      // E uint2 (src, w)
  float*        dinv   = (float*)(ecol + E);                      // n f32
  int*          rowptr = (int*)(dinv + n);                        // n+1 int
  int*          cntM   = rowptr + n + 1;                          // m int
  int*          scanM  = cntM + m;                                // m+1 int
  int*          blocksum = scanM + m + 1;                         // NB_SCAN int
  unsigned int* wt_u1  = (unsigned int*)(blocksum + NB_SCAN);     // 128*32 uint
  unsigned int* wt_f1  = wt_u1 + 128 * 32;                        // 128*64 uint
  unsigned int* wt_c2  = wt_f1 + 128 * 64;                        // 128*64 uint
  float*        bc_u   = (float*)(wt_c2 + 128 * 64);              // 128 f32
  float*        bc_f   = bc_u + 128;                              // 128 f32

  // ---- composed layer-1 weights (embed folded into conv1) + c2 pack ----
  compose_pack_kernel<<<(128 * 32 + 255) / 256, 256, 0, stream>>>(u_W, c1_W, wt_u1, 64);
  compose_pack_kernel<<<(128 * 64 + 255) / 256, 256, 0, stream>>>(f_W, c1_W, wt_f1, 128);
  bias_comp_kernel<<<1, 128, 0, stream>>>(u_b, c1_W, bc_u);
  bias_comp_kernel<<<1, 128, 0, stream>>>(f_b, c1_W, bc_f);
  wt_pack_kernel<<<(128 * 64 + 255) / 256, 256, 0, stream>>>(c2_W, wt_c2, 128);

  // ---- deterministic radix binning of edges by dst bucket ----
  hist_chunk_kernel<<<nchunk, 256, 0, stream>>>(dst, cntM, E, nbuck, nchunk);
  scan_pass1<<<NB_SCAN, NT_SCAN, 0, stream>>>(cntM, blocksum, m);
  scan_pass2<<<1, NB_SCAN, 0, stream>>>(blocksum);
  scan_pass3<<<NB_SCAN, NT_SCAN, 0, stream>>>(cntM, blocksum, scanM, m);
  scatter_chunk_kernel<<<nchunk, 256, 0, stream>>>(src, dst, scanM, ebuf, E, nbuck, nchunk);

  // ---- per-node rowptr/dinv, then per-bucket CSR fill ----
  deg_rowptr_kernel<<<nbuck, 256, 0, stream>>>(ebuf, scanM, rowptr, dinv,
                                               n, nbuck, nchunk, E);
  fill_bucket_kernel<<<nbuck, 256, 0, stream>>>(ebuf, scanM, rowptr, dinv, ecol,
                                                n, nchunk);

  // ---- layer 1: composed dense (embed + conv1 linear) -> xwb ----
  dense_mfma_kernel<64, true><<<(n_u + 31) / 32, 256, 0, stream>>>(
      u_feat, wt_u1, bc_u, nullptr, (__hip_bfloat16*)xwb, n_u);
  dense_mfma_kernel<128, true><<<(n_f + 31) / 32, 256, 0, stream>>>(
      f_feat, wt_f1, bc_f, nullptr, ((__hip_bfloat16*)xwb) + (size_t)n_u * HID, n_f);
  gather_norm_kernel<false><<<(n + 3) / 4, 256, 0, stream>>>(
      rowptr, ecol, (const uint4*)xwb, dinv, c1_b, n1_g, n1_b,
      nullptr, nullptr, x, nullptr, n);

  // ---- layer 2 (fused prediction-head projection) ----
  dense_mfma_kernel<128, true><<<(n + 31) / 32, 256, 0, stream>>>(
      x, wt_c2, nullptr, nullptr, (__hip_bfloat16*)xwb, n);
  gather_norm_kernel<true><<<(n + 3) / 4, 256, 0, stream>>>(
      rowptr, ecol, (const uint4*)xwb, dinv, c2_b, n2_g, n2_b,
      e_W, r_W, nullptr, table, n);

  // ---- per-pair combine ----
  float* out_exist  = (float*)d_out;
  float* out_rating = out_exist + Ep;
  pair_kernel<<<(Ep + 255) / 256, 256, 0, stream>>>(eu, ef, table, e_b, r_b,
                                                    out_exist, out_rating, Ep);
}

// Round 19
// 305.401 us; speedup vs baseline: 1.9800x; 1.0642x over previous
//
#include <hip/hip_runtime.h>
#include <hip/hip_bf16.h>
#include <math.h>

#define HID 128
#define SLOPE 0.01f
#define LN_EPS 1e-5f
#define NB_SCAN 256
#define NT_SCAN 256
#define BSHIFT 6     // 64 dst nodes per bucket
#define CHUNK 8192   // edges per binning block
#define MAXBUCK 1152

typedef __attribute__((ext_vector_type(8))) short bf16x8;
typedef __attribute__((ext_vector_type(4))) float f32x4;

__device__ __forceinline__ float bf16lo(unsigned int v) {
  unsigned int b = v << 16;
  return __builtin_bit_cast(float, b);
}
__device__ __forceinline__ float bf16hi(unsigned int v) {
  unsigned int b = v & 0xFFFF0000u;
  return __builtin_bit_cast(float, b);
}
__device__ __forceinline__ unsigned int pack_bf16(float lo, float hi) {
  __hip_bfloat16 a = __float2bfloat16(lo);
  __hip_bfloat16 b = __float2bfloat16(hi);
  return (unsigned int)__builtin_bit_cast(unsigned short, a) |
         ((unsigned int)__builtin_bit_cast(unsigned short, b) << 16);
}

// Fused weight prep: compose u_W@c1_W (K=64), f_W@c1_W (K=128), pack c2_W,
// bias compositions.  Flat-index partitioned; one launch.
__global__ __launch_bounds__(256) void wt_prep_kernel(
    const float* __restrict__ u_W, const float* __restrict__ f_W,
    const float* __restrict__ c1_W, const float* __restrict__ c2_W,
    const float* __restrict__ u_b, const float* __restrict__ f_b,
    unsigned int* __restrict__ wt_u1, unsigned int* __restrict__ wt_f1,
    unsigned int* __restrict__ wt_c2, float* __restrict__ bc_u,
    float* __restrict__ bc_f) {
  int idx = blockIdx.x * 256 + threadIdx.x;
  if (idx < 4096) {                       // wt_u1: compose, K=64
    int col = idx & 127, k2 = idx >> 7;
    const float* a0 = u_W + (size_t)(2 * k2) * 128;
    const float* a1 = a0 + 128;
    float s0 = 0.0f, s1 = 0.0f;
    for (int m = 0; m < 128; ++m) {
      float bm = c1_W[(size_t)m * 128 + col];
      s0 = fmaf(a0[m], bm, s0);
      s1 = fmaf(a1[m], bm, s1);
    }
    wt_u1[(size_t)col * 32 + k2] = pack_bf16(s0, s1);
  } else if (idx < 12288) {               // wt_f1: compose, K=128
    int i = idx - 4096;
    int col = i & 127, k2 = i >> 7;
    const float* a0 = f_W + (size_t)(2 * k2) * 128;
    const float* a1 = a0 + 128;
    float s0 = 0.0f, s1 = 0.0f;
    for (int m = 0; m < 128; ++m) {
      float bm = c1_W[(size_t)m * 128 + col];
      s0 = fmaf(a0[m], bm, s0);
      s1 = fmaf(a1[m], bm, s1);
    }
    wt_f1[(size_t)col * 64 + k2] = pack_bf16(s0, s1);
  } else if (idx < 20480) {               // wt_c2: transpose+pack
    int i = idx - 12288;
    int col = i & 127, k2 = i >> 7;
    wt_c2[(size_t)col * 64 + k2] =
        pack_bf16(c2_W[(size_t)(2 * k2) * 128 + col],
                  c2_W[(size_t)(2 * k2 + 1) * 128 + col]);
  } else if (idx < 20736) {               // bias compositions
    int i = idx - 20480;
    int j = i & 127;
    const float* bv = (i < 128) ? u_b : f_b;
    float s = 0.0f;
    for (int m = 0; m < 128; ++m) s = fmaf(bv[m], c1_W[(size_t)m * 128 + j], s);
    if (i < 128) bc_u[j] = s; else bc_f[j] = s;
  }
}

// per-chunk LDS histogram over dst buckets -> cntM[b][c]
__global__ __launch_bounds__(256) void hist_chunk_kernel(
    const int* __restrict__ dst, int* __restrict__ cntM,
    int E, int nbuck, int nchunk) {
  __shared__ int hist[MAXBUCK];
  int c = blockIdx.x, tid = threadIdx.x;
  for (int i = tid; i < nbuck; i += 256) hist[i] = 0;
  __syncthreads();
  int beg = c * CHUNK, end = min(beg + CHUNK, E);
  for (int e = beg + tid; e < end; e += 256)
    atomicAdd(&hist[dst[e] >> BSHIFT], 1);
  __syncthreads();
  for (int b = tid; b < nbuck; b += 256)
    cntM[(size_t)b * nchunk + c] = hist[b];
}

// 3-pass exclusive scan over m elements -> scanM[0..m], scanM[m]=total
__global__ void scan_pass1(const int* __restrict__ cnt, int* __restrict__ blocksum, int m) {
  __shared__ int ss[NT_SCAN];
  int K = (m + NB_SCAN * NT_SCAN - 1) / (NB_SCAN * NT_SCAN);
  int t = threadIdx.x, b = blockIdx.x;
  int beg = (b * NT_SCAN + t) * K;
  int end = min(beg + K, m);
  int s = 0;
  for (int i = beg; i < end; ++i) s += cnt[i];
  ss[t] = s;
  __syncthreads();
  for (int off = NT_SCAN / 2; off > 0; off >>= 1) {
    if (t < off) ss[t] += ss[t + off];
    __syncthreads();
  }
  if (t == 0) blocksum[b] = ss[0];
}

__global__ void scan_pass2(int* __restrict__ blocksum) {
  __shared__ int ss[NB_SCAN];
  int t = threadIdx.x;
  ss[t] = blocksum[t];
  __syncthreads();
  for (int off = 1; off < NB_SCAN; off <<= 1) {
    int v = (t >= off) ? ss[t - off] : 0;
    __syncthreads();
    ss[t] += v;
    __syncthreads();
  }
  blocksum[t] = (t == 0) ? 0 : ss[t - 1];
}

__global__ void scan_pass3(const int* __restrict__ cnt, const int* __restrict__ blockoff,
                           int* __restrict__ scanM, int m) {
  __shared__ int ss[NT_SCAN];
  int K = (m + NB_SCAN * NT_SCAN - 1) / (NB_SCAN * NT_SCAN);
  int t = threadIdx.x, b = blockIdx.x;
  int beg = (b * NT_SCAN + t) * K;
  int end = min(beg + K, m);
  int s = 0;
  for (int i = beg; i < end; ++i) s += cnt[i];
  ss[t] = s;
  __syncthreads();
  for (int off = 1; off < NT_SCAN; off <<= 1) {
    int v = (t >= off) ? ss[t - off] : 0;
    __syncthreads();
    ss[t] += v;
    __syncthreads();
  }
  int pre = blockoff[b] + ((t == 0) ? 0 : ss[t - 1]);
  for (int i = beg; i < end; ++i) {
    scanM[i] = pre;
    pre += cnt[i];
    if (i == m - 1) scanM[m] = pre;
  }
}

// deterministic scatter: LDS cursors from scanM, zero global atomics
__global__ __launch_bounds__(256) void scatter_chunk_kernel(
    const int* __restrict__ src, const int* __restrict__ dst,
    const int* __restrict__ scanM, unsigned int* __restrict__ ebuf,
    int E, int nbuck, int nchunk) {
  __shared__ int cur[MAXBUCK];
  int c = blockIdx.x, tid = threadIdx.x;
  for (int b = tid; b < nbuck; b += 256)
    cur[b] = scanM[(size_t)b * nchunk + c];
  __syncthreads();
  int beg = c * CHUNK, end = min(beg + CHUNK, E);
  for (int e = beg + tid; e < end; e += 256) {
    int s = src[e], d = dst[e];
    int pos = atomicAdd(&cur[d >> BSHIFT], 1);
    ebuf[pos] = ((unsigned)s << 6) | ((unsigned)d & 63);
  }
}

// per-bucket: degree count in LDS -> per-node rowptr (bucket base + wave scan),
// dinv.  One block per bucket; bucket range from scanM.
__global__ __launch_bounds__(256) void deg_rowptr_kernel(
    const unsigned int* __restrict__ ebuf, const int* __restrict__ scanM,
    int* __restrict__ rowptr, float* __restrict__ dinv,
    int n, int nbuck, int nchunk, int E) {
  __shared__ int sdeg[64];
  int b = blockIdx.x, tid = threadIdx.x;
  if (tid < 64) sdeg[tid] = 0;
  __syncthreads();
  int beg = scanM[(size_t)b * nchunk], end = scanM[(size_t)(b + 1) * nchunk];
  for (int j = beg + tid; j < end; j += 256) atomicAdd(&sdeg[ebuf[j] & 63], 1);
  __syncthreads();
  if (tid < 64) {
    int deg = sdeg[tid];
    int s = deg;
#pragma unroll
    for (int off = 1; off < 64; off <<= 1) {
      int v = __shfl_up(s, off);
      if (tid >= off) s += v;
    }
    int excl = s - deg;
    int nd = (b << BSHIFT) + tid;
    if (nd < n) {
      rowptr[nd] = beg + excl;
      dinv[nd] = rsqrtf((float)(deg + 1));
    }
    if (b == nbuck - 1 && tid == 0) rowptr[n] = E;
  }
}

// per-bucket CSR fill: LDS cursors, ecol writes in a ~15KB window
__global__ __launch_bounds__(256) void fill_bucket_kernel(
    const unsigned int* __restrict__ ebuf, const int* __restrict__ scanM,
    const int* __restrict__ rowptr, const float* __restrict__ dinv,
    uint2* __restrict__ ecol, int n, int nchunk) {
  __shared__ int scur[64];
  __shared__ int srow[64];
  __shared__ float sdinv[64];
  int b = blockIdx.x, tid = threadIdx.x;
  if (tid < 64) {
    scur[tid] = 0;
    int nd = (b << BSHIFT) + tid;
    srow[tid] = (nd < n) ? rowptr[nd] : 0;
    sdinv[tid] = (nd < n) ? dinv[nd] : 0.0f;
  }
  __syncthreads();
  int beg = scanM[(size_t)b * nchunk], end = scanM[(size_t)(b + 1) * nchunk];
  for (int j = beg + tid; j < end; j += 256) {
    unsigned int v = ebuf[j];
    int ndl = (int)(v & 63);
    int s = (int)(v >> 6);
    int pos = atomicAdd(&scur[ndl], 1);
    float w = dinv[s] * sdinv[ndl];
    ecol[srow[ndl] + pos] = make_uint2((unsigned)s, __builtin_bit_cast(unsigned int, w));
  }
}

// MFMA dense: out[r][j] = bias[j] + sum_k feat[r][k]*bf16(W[k][j]).
// x split hi/lo bf16 (2 MFMAs).  4 waves/block; wave w: rows base+16*(w&1),
// cols 64*(w>>1)..+64.  No LDS.
template<int K, bool BF16OUT>
__global__ __launch_bounds__(256) void dense_mfma_kernel(
    const float* __restrict__ feat, const unsigned int* __restrict__ Wt,
    const float* __restrict__ bias,
    float* __restrict__ outf, __hip_bfloat16* __restrict__ outb, int nrows) {
  int tid = threadIdx.x;
  int wid = tid >> 6, lane = tid & 63;
  int l15 = lane & 15, lk = lane >> 4;
  int rowbase = blockIdx.x * 32 + 16 * (wid & 1);
  int colbase = 64 * (wid >> 1);

  f32x4 acc0 = {}, acc1 = {}, acc2 = {}, acc3 = {};

  int row = rowbase + l15;
  int rrow = min(row, nrows - 1);
  const float* ap0 = feat + (size_t)rrow * K + lk * 8;

#pragma unroll
  for (int kb = 0; kb < K / 32; ++kb) {
    const float* ap = ap0 + kb * 32;
    float4 a0 = *reinterpret_cast<const float4*>(ap);
    float4 a1 = *reinterpret_cast<const float4*>(ap + 4);
    float af0 = a0.x, af1 = a0.y, af2 = a0.z, af3 = a0.w;
    float af4 = a1.x, af5 = a1.y, af6 = a1.z, af7 = a1.w;
    unsigned int b0 = __builtin_bit_cast(unsigned int, af0);
    unsigned int b1 = __builtin_bit_cast(unsigned int, af1);
    unsigned int b2 = __builtin_bit_cast(unsigned int, af2);
    unsigned int b3 = __builtin_bit_cast(unsigned int, af3);
    unsigned int b4 = __builtin_bit_cast(unsigned int, af4);
    unsigned int b5 = __builtin_bit_cast(unsigned int, af5);
    unsigned int b6 = __builtin_bit_cast(unsigned int, af6);
    unsigned int b7 = __builtin_bit_cast(unsigned int, af7);
    uint4 hv;
    hv.x = (b0 >> 16) | (b1 & 0xFFFF0000u);
    hv.y = (b2 >> 16) | (b3 & 0xFFFF0000u);
    hv.z = (b4 >> 16) | (b5 & 0xFFFF0000u);
    hv.w = (b6 >> 16) | (b7 & 0xFFFF0000u);
    uint4 lv;
    {
      float h0 = __builtin_bit_cast(float, b0 & 0xFFFF0000u);
      float h1 = __builtin_bit_cast(float, b1 & 0xFFFF0000u);
      float h2 = __builtin_bit_cast(float, b2 & 0xFFFF0000u);
      float h3 = __builtin_bit_cast(float, b3 & 0xFFFF0000u);
      float h4 = __builtin_bit_cast(float, b4 & 0xFFFF0000u);
      float h5 = __builtin_bit_cast(float, b5 & 0xFFFF0000u);
      float h6 = __builtin_bit_cast(float, b6 & 0xFFFF0000u);
      float h7 = __builtin_bit_cast(float, b7 & 0xFFFF0000u);
      lv.x = pack_bf16(af0 - h0, af1 - h1);
      lv.y = pack_bf16(af2 - h2, af3 - h3);
      lv.z = pack_bf16(af4 - h4, af5 - h5);
      lv.w = pack_bf16(af6 - h6, af7 - h7);
    }
    bf16x8 ahi = __builtin_bit_cast(bf16x8, hv);
    bf16x8 alo = __builtin_bit_cast(bf16x8, lv);

    const unsigned int* wrow = Wt + (size_t)(colbase + l15) * (K / 2) + kb * 16 + lk * 4;
    bf16x8 bf0 = __builtin_bit_cast(bf16x8, *reinterpret_cast<const uint4*>(wrow));
    bf16x8 bf1 = __builtin_bit_cast(bf16x8, *reinterpret_cast<const uint4*>(wrow + 16 * (K / 2)));
    bf16x8 bf2 = __builtin_bit_cast(bf16x8, *reinterpret_cast<const uint4*>(wrow + 32 * (K / 2)));
    bf16x8 bf3 = __builtin_bit_cast(bf16x8, *reinterpret_cast<const uint4*>(wrow + 48 * (K / 2)));
    acc0 = __builtin_amdgcn_mfma_f32_16x16x32_bf16(ahi, bf0, acc0, 0, 0, 0);
    acc0 = __builtin_amdgcn_mfma_f32_16x16x32_bf16(alo, bf0, acc0, 0, 0, 0);
    acc1 = __builtin_amdgcn_mfma_f32_16x16x32_bf16(ahi, bf1, acc1, 0, 0, 0);
    acc1 = __builtin_amdgcn_mfma_f32_16x16x32_bf16(alo, bf1, acc1, 0, 0, 0);
    acc2 = __builtin_amdgcn_mfma_f32_16x16x32_bf16(ahi, bf2, acc2, 0, 0, 0);
    acc2 = __builtin_amdgcn_mfma_f32_16x16x32_bf16(alo, bf2, acc2, 0, 0, 0);
    acc3 = __builtin_amdgcn_mfma_f32_16x16x32_bf16(ahi, bf3, acc3, 0, 0, 0);
    acc3 = __builtin_amdgcn_mfma_f32_16x16x32_bf16(alo, bf3, acc3, 0, 0, 0);
  }

#pragma unroll
  for (int t = 0; t < 4; ++t) {
    int col = colbase + 16 * t + l15;
    float bv = bias ? bias[col] : 0.0f;
    f32x4 a = (t == 0) ? acc0 : (t == 1) ? acc1 : (t == 2) ? acc2 : acc3;
#pragma unroll
    for (int r = 0; r < 4; ++r) {
      int orow = rowbase + lk * 4 + r;
      if (orow < nrows) {
        float v = a[r] + bv;
        if (BF16OUT) outb[(size_t)orow * HID + col] = __float2bfloat16(v);
        else         outf[(size_t)orow * HID + col] = v;
      }
    }
  }
}

// One wave per dst node; 4 lane-groups of 16; unroll x4 (edges j..j+12 per
// iter, ascending accumulate => bit-exact vs stride-4 loop).
template<bool PROJ>
__global__ void gather_norm_kernel(const int* __restrict__ rowptr,
                                   const uint2* __restrict__ ecol,
                                   const uint4* __restrict__ xwb4,
                                   const float* __restrict__ dinv,
                                   const float* __restrict__ cb,
                                   const float* __restrict__ g,
                                   const float* __restrict__ b,
                                   const float* __restrict__ eW,
                                   const float* __restrict__ rW,
                                   float* __restrict__ outx,
                                   float4* __restrict__ table, int n_nodes) {
  int d = blockIdx.x * 4 + (threadIdx.x >> 6);
  if (d >= n_nodes) return;
  int lane = threadIdx.x & 63;
  int grp = lane >> 4;
  int t = lane & 15;

  float acc[8];
#pragma unroll
  for (int k = 0; k < 8; ++k) acc[k] = 0.0f;

  float wd = dinv[d];
  int beg = rowptr[d], end = rowptr[d + 1];
  int j = beg + grp;
  for (; j + 12 < end; j += 16) {
    uint2 e0 = ecol[j];
    uint2 e1 = ecol[j + 4];
    uint2 e2 = ecol[j + 8];
    uint2 e3 = ecol[j + 12];
    uint4 v0 = xwb4[(size_t)e0.x * 16 + t];
    uint4 v1 = xwb4[(size_t)e1.x * 16 + t];
    uint4 v2 = xwb4[(size_t)e2.x * 16 + t];
    uint4 v3 = xwb4[(size_t)e3.x * 16 + t];
    float w0 = __builtin_bit_cast(float, e0.y);
    float w1 = __builtin_bit_cast(float, e1.y);
    float w2 = __builtin_bit_cast(float, e2.y);
    float w3 = __builtin_bit_cast(float, e3.y);
    acc[0] = fmaf(bf16lo(v0.x), w0, acc[0]);
    acc[1] = fmaf(bf16hi(v0.x), w0, acc[1]);
    acc[2] = fmaf(bf16lo(v0.y), w0, acc[2]);
    acc[3] = fmaf(bf16hi(v0.y), w0, acc[3]);
    acc[4] = fmaf(bf16lo(v0.z), w0, acc[4]);
    acc[5] = fmaf(bf16hi(v0.z), w0, acc[5]);
    acc[6] = fmaf(bf16lo(v0.w), w0, acc[6]);
    acc[7] = fmaf(bf16hi(v0.w), w0, acc[7]);
    acc[0] = fmaf(bf16lo(v1.x), w1, acc[0]);
    acc[1] = fmaf(bf16hi(v1.x), w1, acc[1]);
    acc[2] = fmaf(bf16lo(v1.y), w1, acc[2]);
    acc[3] = fmaf(bf16hi(v1.y), w1, acc[3]);
    acc[4] = fmaf(bf16lo(v1.z), w1, acc[4]);
    acc[5] = fmaf(bf16hi(v1.z), w1, acc[5]);
    acc[6] = fmaf(bf16lo(v1.w), w1, acc[6]);
    acc[7] = fmaf(bf16hi(v1.w), w1, acc[7]);
    acc[0] = fmaf(bf16lo(v2.x), w2, acc[0]);
    acc[1] = fmaf(bf16hi(v2.x), w2, acc[1]);
    acc[2] = fmaf(bf16lo(v2.y), w2, acc[2]);
    acc[3] = fmaf(bf16hi(v2.y), w2, acc[3]);
    acc[4] = fmaf(bf16lo(v2.z), w2, acc[4]);
    acc[5] = fmaf(bf16hi(v2.z), w2, acc[5]);
    acc[6] = fmaf(bf16lo(v2.w), w2, acc[6]);
    acc[7] = fmaf(bf16hi(v2.w), w2, acc[7]);
    acc[0] = fmaf(bf16lo(v3.x), w3, acc[0]);
    acc[1] = fmaf(bf16hi(v3.x), w3, acc[1]);
    acc[2] = fmaf(bf16lo(v3.y), w3, acc[2]);
    acc[3] = fmaf(bf16hi(v3.y), w3, acc[3]);
    acc[4] = fmaf(bf16lo(v3.z), w3, acc[4]);
    acc[5] = fmaf(bf16hi(v3.z), w3, acc[5]);
    acc[6] = fmaf(bf16lo(v3.w), w3, acc[6]);
    acc[7] = fmaf(bf16hi(v3.w), w3, acc[7]);
  }
  for (; j < end; j += 4) {
    uint2 e0 = ecol[j];
    uint4 v0 = xwb4[(size_t)e0.x * 16 + t];
    float w0 = __builtin_bit_cast(float, e0.y);
    acc[0] = fmaf(bf16lo(v0.x), w0, acc[0]);
    acc[1] = fmaf(bf16hi(v0.x), w0, acc[1]);
    acc[2] = fmaf(bf16lo(v0.y), w0, acc[2]);
    acc[3] = fmaf(bf16hi(v0.y), w0, acc[3]);
    acc[4] = fmaf(bf16lo(v0.z), w0, acc[4]);
    acc[5] = fmaf(bf16hi(v0.z), w0, acc[5]);
    acc[6] = fmaf(bf16lo(v0.w), w0, acc[6]);
    acc[7] = fmaf(bf16hi(v0.w), w0, acc[7]);
  }
#pragma unroll
  for (int k = 0; k < 8; ++k) {
    acc[k] += __shfl_xor(acc[k], 16);
    acc[k] += __shfl_xor(acc[k], 32);
  }
  {
    float wself = wd * wd;
    uint4 v = xwb4[(size_t)d * 16 + t];
    acc[0] = fmaf(bf16lo(v.x), wself, acc[0]);
    acc[1] = fmaf(bf16hi(v.x), wself, acc[1]);
    acc[2] = fmaf(bf16lo(v.y), wself, acc[2]);
    acc[3] = fmaf(bf16hi(v.y), wself, acc[3]);
    acc[4] = fmaf(bf16lo(v.z), wself, acc[4]);
    acc[5] = fmaf(bf16hi(v.z), wself, acc[5]);
    acc[6] = fmaf(bf16lo(v.w), wself, acc[6]);
    acc[7] = fmaf(bf16hi(v.w), wself, acc[7]);
    float4 c0 = *reinterpret_cast<const float4*>(cb + 8 * t);
    float4 c1 = *reinterpret_cast<const float4*>(cb + 8 * t + 4);
    acc[0] += c0.x; acc[1] += c0.y; acc[2] += c0.z; acc[3] += c0.w;
    acc[4] += c1.x; acc[5] += c1.y; acc[6] += c1.z; acc[7] += c1.w;
  }
  float s = acc[0] + acc[1] + acc[2] + acc[3] + acc[4] + acc[5] + acc[6] + acc[7];
#pragma unroll
  for (int m = 1; m < 16; m <<= 1) s += __shfl_xor(s, m);
  float mu = s * (1.0f / HID);
  float sq = 0.0f;
#pragma unroll
  for (int k = 0; k < 8; ++k) {
    acc[k] -= mu;
    sq = fmaf(acc[k], acc[k], sq);
  }
#pragma unroll
  for (int m = 1; m < 16; m <<= 1) sq += __shfl_xor(sq, m);
  float rs = rsqrtf(sq * (1.0f / HID) + LN_EPS);
  float4 g0 = *reinterpret_cast<const float4*>(g + 8 * t);
  float4 g1 = *reinterpret_cast<const float4*>(g + 8 * t + 4);
  float4 b0 = *reinterpret_cast<const float4*>(b + 8 * t);
  float4 b1 = *reinterpret_cast<const float4*>(b + 8 * t + 4);
  float o[8];
  o[0] = acc[0] * rs * g0.x + b0.x;
  o[1] = acc[1] * rs * g0.y + b0.y;
  o[2] = acc[2] * rs * g0.z + b0.z;
  o[3] = acc[3] * rs * g0.w + b0.w;
  o[4] = acc[4] * rs * g1.x + b1.x;
  o[5] = acc[5] * rs * g1.y + b1.y;
  o[6] = acc[6] * rs * g1.z + b1.z;
  o[7] = acc[7] * rs * g1.w + b1.w;
#pragma unroll
  for (int k = 0; k < 8; ++k) o[k] = o[k] >= 0.0f ? o[k] : SLOPE * o[k];

  if (!PROJ) {
    if (grp == 0) {
      float4* op = reinterpret_cast<float4*>(outx + (size_t)d * HID + 8 * t);
      op[0] = make_float4(o[0], o[1], o[2], o[3]);
      op[1] = make_float4(o[4], o[5], o[6], o[7]);
    }
  } else {
    float4 eu0 = *reinterpret_cast<const float4*>(eW + 8 * t);
    float4 eu1 = *reinterpret_cast<const float4*>(eW + 8 * t + 4);
    float4 ef0 = *reinterpret_cast<const float4*>(eW + HID + 8 * t);
    float4 ef1 = *reinterpret_cast<const float4*>(eW + HID + 8 * t + 4);
    float4 ru0 = *reinterpret_cast<const float4*>(rW + 8 * t);
    float4 ru1 = *reinterpret_cast<const float4*>(rW + 8 * t + 4);
    float4 rf0 = *reinterpret_cast<const float4*>(rW + HID + 8 * t);
    float4 rf1 = *reinterpret_cast<const float4*>(rW + HID + 8 * t + 4);
    float pa = o[0]*eu0.x + o[1]*eu0.y + o[2]*eu0.z + o[3]*eu0.w
             + o[4]*eu1.x + o[5]*eu1.y + o[6]*eu1.z + o[7]*eu1.w;
    float pb = o[0]*ef0.x + o[1]*ef0.y + o[2]*ef0.z + o[3]*ef0.w
             + o[4]*ef1.x + o[5]*ef1.y + o[6]*ef1.z + o[7]*ef1.w;
    float pc = o[0]*ru0.x + o[1]*ru0.y + o[2]*ru0.z + o[3]*ru0.w
             + o[4]*ru1.x + o[5]*ru1.y + o[6]*ru1.z + o[7]*ru1.w;
    float pd = o[0]*rf0.x + o[1]*rf0.y + o[2]*rf0.z + o[3]*rf0.w
             + o[4]*rf1.x + o[5]*rf1.y + o[6]*rf1.z + o[7]*rf1.w;
#pragma unroll
    for (int m = 1; m < 16; m <<= 1) {
      pa += __shfl_xor(pa, m);
      pb += __shfl_xor(pb, m);
      pc += __shfl_xor(pc, m);
      pd += __shfl_xor(pd, m);
    }
    if (lane == 0) table[d] = make_float4(pa, pb, pc, pd);
  }
}

// one thread per prediction pair
__global__ void pair_kernel(const int* __restrict__ eu, const int* __restrict__ ef,
                            const float4* __restrict__ table,
                            const float* __restrict__ eb, const float* __restrict__ rb,
                            float* __restrict__ out_exist, float* __restrict__ out_rating,
                            int Ep) {
  int i = blockIdx.x * blockDim.x + threadIdx.x;
  if (i >= Ep) return;
  float4 tu = table[eu[i]];
  float4 tf = table[ef[i]];
  float pe = tu.x + tf.y + eb[0];
  float pr = tu.z + tf.w + rb[0];
  out_exist[i]  = 1.0f / (1.0f + expf(-pe));
  out_rating[i] = 1.0f + 4.0f / (1.0f + expf(-pr));
}

extern "C" void kernel_launch(void* const* d_in, const int* in_sizes, int n_in,
                              void* d_out, int out_size, void* d_ws, size_t ws_size,
                              hipStream_t stream) {
  const float* u_feat = (const float*)d_in[0];
  const float* f_feat = (const float*)d_in[1];
  const int*   ei     = (const int*)d_in[2];
  const int*   eu     = (const int*)d_in[3];
  const int*   ef     = (const int*)d_in[4];
  const float* u_W  = (const float*)d_in[5];
  const float* u_b  = (const float*)d_in[6];
  const float* f_W  = (const float*)d_in[7];
  const float* f_b  = (const float*)d_in[8];
  const float* c1_W = (const float*)d_in[9];
  const float* c1_b = (const float*)d_in[10];
  const float* c2_W = (const float*)d_in[11];
  const float* c2_b = (const float*)d_in[12];
  const float* n1_g = (const float*)d_in[13];
  const float* n1_b = (const float*)d_in[14];
  const float* n2_g = (const float*)d_in[15];
  const float* n2_b = (const float*)d_in[16];
  const float* e_W  = (const float*)d_in[17];
  const float* e_b  = (const float*)d_in[18];
  const float* r_W  = (const float*)d_in[19];
  const float* r_b  = (const float*)d_in[20];

  int n_u = in_sizes[0] / 64;
  int n_f = in_sizes[1] / HID;
  int n   = n_u + n_f;
  int E   = in_sizes[2] / 2;
  int Ep  = in_sizes[3];
  int nbuck  = (n + (1 << BSHIFT) - 1) >> BSHIFT;
  int nchunk = (E + CHUNK - 1) / CHUNK;
  int m      = nbuck * nchunk;

  const int* src = ei;
  const int* dst = ei + E;

  float*        x      = (float*)d_ws;                            // n*HID f32
  unsigned int* xwb    = (unsigned int*)(x + (size_t)n * HID);    // n*HID/2 uint
  float4*       table  = (float4*)(xwb + (size_t)n * (HID / 2));  // n float4
  unsigned int* ebuf   = (unsigned int*)(table + n);              // E uint (packed)
  uint2*        ecol   = (uint2*)(ebuf + E);                      // E uint2 (src, w)
  float*        dinv   = (float*)(ecol + E);                      // n f32
  int*          rowptr = (int*)(dinv + n);                        // n+1 int
  int*          cntM   = rowptr + n + 1;                          // m int
  int*          scanM  = cntM + m;                                // m+1 int
  int*          blocksum = scanM + m + 1;                         // NB_SCAN int
  unsigned int* wt_u1  = (unsigned int*)(blocksum + NB_SCAN);     // 128*32 uint
  unsigned int* wt_f1  = wt_u1 + 128 * 32;                        // 128*64 uint
  unsigned int* wt_c2  = wt_f1 + 128 * 64;                        // 128*64 uint
  float*        bc_u   = (float*)(wt_c2 + 128 * 64);              // 128 f32
  float*        bc_f   = bc_u + 128;                              // 128 f32

  // ---- fused weight prep (composed layer-1 + c2 pack + biases) ----
  wt_prep_kernel<<<81, 256, 0, stream>>>(u_W, f_W, c1_W, c2_W, u_b, f_b,
                                         wt_u1, wt_f1, wt_c2, bc_u, bc_f);

  // ---- deterministic radix binning of edges by dst bucket ----
  hist_chunk_kernel<<<nchunk, 256, 0, stream>>>(dst, cntM, E, nbuck, nchunk);
  scan_pass1<<<NB_SCAN, NT_SCAN, 0, stream>>>(cntM, blocksum, m);
  scan_pass2<<<1, NB_SCAN, 0, stream>>>(blocksum);
  scan_pass3<<<NB_SCAN, NT_SCAN, 0, stream>>>(cntM, blocksum, scanM, m);
  scatter_chunk_kernel<<<nchunk, 256, 0, stream>>>(src, dst, scanM, ebuf, E, nbuck, nchunk);

  // ---- per-node rowptr/dinv, then per-bucket CSR fill ----
  deg_rowptr_kernel<<<nbuck, 256, 0, stream>>>(ebuf, scanM, rowptr, dinv,
                                               n, nbuck, nchunk, E);
  fill_bucket_kernel<<<nbuck, 256, 0, stream>>>(ebuf, scanM, rowptr, dinv, ecol,
                                                n, nchunk);

  // ---- layer 1: composed dense (embed + conv1 linear) -> xwb ----
  dense_mfma_kernel<64, true><<<(n_u + 31) / 32, 256, 0, stream>>>(
      u_feat, wt_u1, bc_u, nullptr, (__hip_bfloat16*)xwb, n_u);
  dense_mfma_kernel<128, true><<<(n_f + 31) / 32, 256, 0, stream>>>(
      f_feat, wt_f1, bc_f, nullptr, ((__hip_bfloat16*)xwb) + (size_t)n_u * HID, n_f);
  gather_norm_kernel<false><<<(n + 3) / 4, 256, 0, stream>>>(
      rowptr, ecol, (const uint4*)xwb, dinv, c1_b, n1_g, n1_b,
      nullptr, nullptr, x, nullptr, n);

  // ---- layer 2 (fused prediction-head projection) ----
  dense_mfma_kernel<128, true><<<(n + 31) / 32, 256, 0, stream>>>(
      x, wt_c2, nullptr, nullptr, (__hip_bfloat16*)xwb, n);
  gather_norm_kernel<true><<<(n + 3) / 4, 256, 0, stream>>>(
      rowptr, ecol, (const uint4*)xwb, dinv, c2_b, n2_g, n2_b,
      e_W, r_W, nullptr, table, n);

  // ---- per-pair combine ----
  float* out_exist  = (float*)d_out;
  float* out_rating = out_exist + Ep;
  pair_kernel<<<(Ep + 255) / 256, 256, 0, stream>>>(eu, ef, table, e_b, r_b,
                                                    out_exist, out_rating, Ep);
}

// Round 20
// 293.959 us; speedup vs baseline: 2.0571x; 1.0389x over previous
//
#include <hip/hip_runtime.h>
#include <hip/hip_bf16.h>
#include <math.h>

#define HID 128
#define SLOPE 0.01f
#define LN_EPS 1e-5f
#define NB_SCAN 256
#define NT_SCAN 256
#define BSHIFT 6     // 64 dst nodes per bucket
#define CHUNK 8192   // edges per binning block
#define MAXBUCK 1152
#define WPREP_BLOCKS 81

typedef __attribute__((ext_vector_type(8))) short bf16x8;
typedef __attribute__((ext_vector_type(4))) float f32x4;

__device__ __forceinline__ float bf16lo(unsigned int v) {
  unsigned int b = v << 16;
  return __builtin_bit_cast(float, b);
}
__device__ __forceinline__ float bf16hi(unsigned int v) {
  unsigned int b = v & 0xFFFF0000u;
  return __builtin_bit_cast(float, b);
}
__device__ __forceinline__ unsigned int pack_bf16(float lo, float hi) {
  __hip_bfloat16 a = __float2bfloat16(lo);
  __hip_bfloat16 b = __float2bfloat16(hi);
  return (unsigned int)__builtin_bit_cast(unsigned short, a) |
         ((unsigned int)__builtin_bit_cast(unsigned short, b) << 16);
}

// Fused: blocks [0,WPREP_BLOCKS) do weight prep; blocks >= WPREP_BLOCKS do the
// per-chunk dst-bucket histogram.  (Independent work, one launch.)
__global__ __launch_bounds__(256) void prep_hist_kernel(
    const float* __restrict__ u_W, const float* __restrict__ f_W,
    const float* __restrict__ c1_W, const float* __restrict__ c2_W,
    const float* __restrict__ u_b, const float* __restrict__ f_b,
    unsigned int* __restrict__ wt_u1, unsigned int* __restrict__ wt_f1,
    unsigned int* __restrict__ wt_c2, float* __restrict__ bc_u,
    float* __restrict__ bc_f,
    const int* __restrict__ dst, int* __restrict__ cntM,
    int E, int nbuck, int nchunk) {
  __shared__ int hist[MAXBUCK];
  if (blockIdx.x >= WPREP_BLOCKS) {
    int c = blockIdx.x - WPREP_BLOCKS, tid = threadIdx.x;
    for (int i = tid; i < nbuck; i += 256) hist[i] = 0;
    __syncthreads();
    int beg = c * CHUNK, end = min(beg + CHUNK, E);
    int e = beg + 2 * tid;
    for (; e + 1 < end; e += 512) {
      int2 d2 = *reinterpret_cast<const int2*>(&dst[e]);
      atomicAdd(&hist[d2.x >> BSHIFT], 1);
      atomicAdd(&hist[d2.y >> BSHIFT], 1);
    }
    if (e < end) atomicAdd(&hist[dst[e] >> BSHIFT], 1);
    __syncthreads();
    for (int b = tid; b < nbuck; b += 256)
      cntM[(size_t)b * nchunk + c] = hist[b];
    return;
  }
  int idx = blockIdx.x * 256 + threadIdx.x;
  if (idx < 4096) {                       // wt_u1: compose u_W@c1_W, K=64
    int col = idx & 127, k2 = idx >> 7;
    const float* a0 = u_W + (size_t)(2 * k2) * 128;
    const float* a1 = a0 + 128;
    float s0 = 0.0f, s1 = 0.0f;
    for (int m = 0; m < 128; ++m) {
      float bm = c1_W[(size_t)m * 128 + col];
      s0 = fmaf(a0[m], bm, s0);
      s1 = fmaf(a1[m], bm, s1);
    }
    wt_u1[(size_t)col * 32 + k2] = pack_bf16(s0, s1);
  } else if (idx < 12288) {               // wt_f1: compose f_W@c1_W, K=128
    int i = idx - 4096;
    int col = i & 127, k2 = i >> 7;
    const float* a0 = f_W + (size_t)(2 * k2) * 128;
    const float* a1 = a0 + 128;
    float s0 = 0.0f, s1 = 0.0f;
    for (int m = 0; m < 128; ++m) {
      float bm = c1_W[(size_t)m * 128 + col];
      s0 = fmaf(a0[m], bm, s0);
      s1 = fmaf(a1[m], bm, s1);
    }
    wt_f1[(size_t)col * 64 + k2] = pack_bf16(s0, s1);
  } else if (idx < 20480) {               // wt_c2: transpose+pack
    int i = idx - 12288;
    int col = i & 127, k2 = i >> 7;
    wt_c2[(size_t)col * 64 + k2] =
        pack_bf16(c2_W[(size_t)(2 * k2) * 128 + col],
                  c2_W[(size_t)(2 * k2 + 1) * 128 + col]);
  } else if (idx < 20736) {               // bias compositions
    int i = idx - 20480;
    int j = i & 127;
    const float* bv = (i < 128) ? u_b : f_b;
    float s = 0.0f;
    for (int m = 0; m < 128; ++m) s = fmaf(bv[m], c1_W[(size_t)m * 128 + j], s);
    if (i < 128) bc_u[j] = s; else bc_f[j] = s;
  }
}

// pass1: per-block sums of cntM
__global__ void scan_pass1(const int* __restrict__ cnt, int* __restrict__ blocksum, int m) {
  __shared__ int ss[NT_SCAN];
  int K = (m + NB_SCAN * NT_SCAN - 1) / (NB_SCAN * NT_SCAN);
  int t = threadIdx.x, b = blockIdx.x;
  int beg = (b * NT_SCAN + t) * K;
  int end = min(beg + K, m);
  int s = 0;
  for (int i = beg; i < end; ++i) s += cnt[i];
  ss[t] = s;
  __syncthreads();
  for (int off = NT_SCAN / 2; off > 0; off >>= 1) {
    if (t < off) ss[t] += ss[t + off];
    __syncthreads();
  }
  if (t == 0) blocksum[b] = ss[0];
}

// pass3: each block redundantly scans the 256 block sums in LDS (pass2 folded),
// then writes its exclusive-scan slice of scanM.
__global__ void scan_pass3(const int* __restrict__ cnt, const int* __restrict__ blocksum,
                           int* __restrict__ scanM, int m) {
  __shared__ int ss[NT_SCAN];
  __shared__ int sb[NB_SCAN];
  int K = (m + NB_SCAN * NT_SCAN - 1) / (NB_SCAN * NT_SCAN);
  int t = threadIdx.x, b = blockIdx.x;
  // local exclusive scan of blocksum
  sb[t] = blocksum[t];
  __syncthreads();
  for (int off = 1; off < NB_SCAN; off <<= 1) {
    int v = (t >= off) ? sb[t - off] : 0;
    __syncthreads();
    sb[t] += v;
    __syncthreads();
  }
  int blockoff = (b == 0) ? 0 : sb[b - 1];
  int beg = (b * NT_SCAN + t) * K;
  int end = min(beg + K, m);
  int s = 0;
  for (int i = beg; i < end; ++i) s += cnt[i];
  ss[t] = s;
  __syncthreads();
  for (int off = 1; off < NT_SCAN; off <<= 1) {
    int v = (t >= off) ? ss[t - off] : 0;
    __syncthreads();
    ss[t] += v;
    __syncthreads();
  }
  int pre = blockoff + ((t == 0) ? 0 : ss[t - 1]);
  for (int i = beg; i < end; ++i) {
    scanM[i] = pre;
    pre += cnt[i];
    if (i == m - 1) scanM[m] = pre;
  }
}

// deterministic scatter: LDS cursors from scanM, zero global atomics
__global__ __launch_bounds__(256) void scatter_chunk_kernel(
    const int* __restrict__ src, const int* __restrict__ dst,
    const int* __restrict__ scanM, unsigned int* __restrict__ ebuf,
    int E, int nbuck, int nchunk) {
  __shared__ int cur[MAXBUCK];
  int c = blockIdx.x, tid = threadIdx.x;
  for (int b = tid; b < nbuck; b += 256)
    cur[b] = scanM[(size_t)b * nchunk + c];
  __syncthreads();
  int beg = c * CHUNK, end = min(beg + CHUNK, E);
  int e = beg + 2 * tid;
  for (; e + 1 < end; e += 512) {
    int2 s2 = *reinterpret_cast<const int2*>(&src[e]);
    int2 d2 = *reinterpret_cast<const int2*>(&dst[e]);
    int p0 = atomicAdd(&cur[d2.x >> BSHIFT], 1);
    ebuf[p0] = ((unsigned)s2.x << 6) | ((unsigned)d2.x & 63);
    int p1 = atomicAdd(&cur[d2.y >> BSHIFT], 1);
    ebuf[p1] = ((unsigned)s2.y << 6) | ((unsigned)d2.y & 63);
  }
  if (e < end) {
    int s = src[e], d = dst[e];
    int pos = atomicAdd(&cur[d >> BSHIFT], 1);
    ebuf[pos] = ((unsigned)s << 6) | ((unsigned)d & 63);
  }
}

// per-bucket: degree count in LDS -> per-node rowptr (bucket base + wave scan),
// dinv.  One block per bucket; bucket range from scanM.  uint2 ebuf reads.
__global__ __launch_bounds__(256) void deg_rowptr_kernel(
    const unsigned int* __restrict__ ebuf, const int* __restrict__ scanM,
    int* __restrict__ rowptr, float* __restrict__ dinv,
    int n, int nbuck, int nchunk, int E) {
  __shared__ int sdeg[64];
  int b = blockIdx.x, tid = threadIdx.x;
  if (tid < 64) sdeg[tid] = 0;
  __syncthreads();
  int beg = scanM[(size_t)b * nchunk], end = scanM[(size_t)(b + 1) * nchunk];
  int j = beg + 2 * tid;
  for (; j + 1 < end; j += 512) {
    uint2 v2 = *reinterpret_cast<const uint2*>(&ebuf[j]);
    atomicAdd(&sdeg[v2.x & 63], 1);
    atomicAdd(&sdeg[v2.y & 63], 1);
  }
  if (j < end) atomicAdd(&sdeg[ebuf[j] & 63], 1);
  __syncthreads();
  if (tid < 64) {
    int deg = sdeg[tid];
    int s = deg;
#pragma unroll
    for (int off = 1; off < 64; off <<= 1) {
      int v = __shfl_up(s, off);
      if (tid >= off) s += v;
    }
    int excl = s - deg;
    int nd = (b << BSHIFT) + tid;
    if (nd < n) {
      rowptr[nd] = beg + excl;
      dinv[nd] = rsqrtf((float)(deg + 1));
    }
    if (b == nbuck - 1 && tid == 0) rowptr[n] = E;
  }
}

// per-bucket CSR fill: LDS cursors, ecol writes in a ~15KB window; uint2 reads
__global__ __launch_bounds__(256) void fill_bucket_kernel(
    const unsigned int* __restrict__ ebuf, const int* __restrict__ scanM,
    const int* __restrict__ rowptr, const float* __restrict__ dinv,
    uint2* __restrict__ ecol, int n, int nchunk) {
  __shared__ int scur[64];
  __shared__ int srow[64];
  __shared__ float sdinv[64];
  int b = blockIdx.x, tid = threadIdx.x;
  if (tid < 64) {
    scur[tid] = 0;
    int nd = (b << BSHIFT) + tid;
    srow[tid] = (nd < n) ? rowptr[nd] : 0;
    sdinv[tid] = (nd < n) ? dinv[nd] : 0.0f;
  }
  __syncthreads();
  int beg = scanM[(size_t)b * nchunk], end = scanM[(size_t)(b + 1) * nchunk];
  int j = beg + 2 * tid;
  for (; j + 1 < end; j += 512) {
    uint2 v2 = *reinterpret_cast<const uint2*>(&ebuf[j]);
    {
      int ndl = (int)(v2.x & 63);
      int s = (int)(v2.x >> 6);
      int pos = atomicAdd(&scur[ndl], 1);
      float w = dinv[s] * sdinv[ndl];
      ecol[srow[ndl] + pos] = make_uint2((unsigned)s, __builtin_bit_cast(unsigned int, w));
    }
    {
      int ndl = (int)(v2.y & 63);
      int s = (int)(v2.y >> 6);
      int pos = atomicAdd(&scur[ndl], 1);
      float w = dinv[s] * sdinv[ndl];
      ecol[srow[ndl] + pos] = make_uint2((unsigned)s, __builtin_bit_cast(unsigned int, w));
    }
  }
  if (j < end) {
    unsigned int v = ebuf[j];
    int ndl = (int)(v & 63);
    int s = (int)(v >> 6);
    int pos = atomicAdd(&scur[ndl], 1);
    float w = dinv[s] * sdinv[ndl];
    ecol[srow[ndl] + pos] = make_uint2((unsigned)s, __builtin_bit_cast(unsigned int, w));
  }
}

// MFMA dense: out[r][j] = bias[j] + sum_k feat[r][k]*bf16(W[k][j]).
// x split hi/lo bf16 (2 MFMAs).  4 waves/block; wave w: rows base+16*(w&1),
// cols 64*(w>>1)..+64.  No LDS.
template<int K, bool BF16OUT>
__global__ __launch_bounds__(256) void dense_mfma_kernel(
    const float* __restrict__ feat, const unsigned int* __restrict__ Wt,
    const float* __restrict__ bias,
    float* __restrict__ outf, __hip_bfloat16* __restrict__ outb, int nrows) {
  int tid = threadIdx.x;
  int wid = tid >> 6, lane = tid & 63;
  int l15 = lane & 15, lk = lane >> 4;
  int rowbase = blockIdx.x * 32 + 16 * (wid & 1);
  int colbase = 64 * (wid >> 1);

  f32x4 acc0 = {}, acc1 = {}, acc2 = {}, acc3 = {};

  int row = rowbase + l15;
  int rrow = min(row, nrows - 1);
  const float* ap0 = feat + (size_t)rrow * K + lk * 8;

#pragma unroll
  for (int kb = 0; kb < K / 32; ++kb) {
    const float* ap = ap0 + kb * 32;
    float4 a0 = *reinterpret_cast<const float4*>(ap);
    float4 a1 = *reinterpret_cast<const float4*>(ap + 4);
    float af0 = a0.x, af1 = a0.y, af2 = a0.z, af3 = a0.w;
    float af4 = a1.x, af5 = a1.y, af6 = a1.z, af7 = a1.w;
    unsigned int b0 = __builtin_bit_cast(unsigned int, af0);
    unsigned int b1 = __builtin_bit_cast(unsigned int, af1);
    unsigned int b2 = __builtin_bit_cast(unsigned int, af2);
    unsigned int b3 = __builtin_bit_cast(unsigned int, af3);
    unsigned int b4 = __builtin_bit_cast(unsigned int, af4);
    unsigned int b5 = __builtin_bit_cast(unsigned int, af5);
    unsigned int b6 = __builtin_bit_cast(unsigned int, af6);
    unsigned int b7 = __builtin_bit_cast(unsigned int, af7);
    uint4 hv;
    hv.x = (b0 >> 16) | (b1 & 0xFFFF0000u);
    hv.y = (b2 >> 16) | (b3 & 0xFFFF0000u);
    hv.z = (b4 >> 16) | (b5 & 0xFFFF0000u);
    hv.w = (b6 >> 16) | (b7 & 0xFFFF0000u);
    uint4 lv;
    {
      float h0 = __builtin_bit_cast(float, b0 & 0xFFFF0000u);
      float h1 = __builtin_bit_cast(float, b1 & 0xFFFF0000u);
      float h2 = __builtin_bit_cast(float, b2 & 0xFFFF0000u);
      float h3 = __builtin_bit_cast(float, b3 & 0xFFFF0000u);
      float h4 = __builtin_bit_cast(float, b4 & 0xFFFF0000u);
      float h5 = __builtin_bit_cast(float, b5 & 0xFFFF0000u);
      float h6 = __builtin_bit_cast(float, b6 & 0xFFFF0000u);
      float h7 = __builtin_bit_cast(float, b7 & 0xFFFF0000u);
      lv.x = pack_bf16(af0 - h0, af1 - h1);
      lv.y = pack_bf16(af2 - h2, af3 - h3);
      lv.z = pack_bf16(af4 - h4, af5 - h5);
      lv.w = pack_bf16(af6 - h6, af7 - h7);
    }
    bf16x8 ahi = __builtin_bit_cast(bf16x8, hv);
    bf16x8 alo = __builtin_bit_cast(bf16x8, lv);

    const unsigned int* wrow = Wt + (size_t)(colbase + l15) * (K / 2) + kb * 16 + lk * 4;
    bf16x8 bf0 = __builtin_bit_cast(bf16x8, *reinterpret_cast<const uint4*>(wrow));
    bf16x8 bf1 = __builtin_bit_cast(bf16x8, *reinterpret_cast<const uint4*>(wrow + 16 * (K / 2)));
    bf16x8 bf2 = __builtin_bit_cast(bf16x8, *reinterpret_cast<const uint4*>(wrow + 32 * (K / 2)));
    bf16x8 bf3 = __builtin_bit_cast(bf16x8, *reinterpret_cast<const uint4*>(wrow + 48 * (K / 2)));
    acc0 = __builtin_amdgcn_mfma_f32_16x16x32_bf16(ahi, bf0, acc0, 0, 0, 0);
    acc0 = __builtin_amdgcn_mfma_f32_16x16x32_bf16(alo, bf0, acc0, 0, 0, 0);
    acc1 = __builtin_amdgcn_mfma_f32_16x16x32_bf16(ahi, bf1, acc1, 0, 0, 0);
    acc1 = __builtin_amdgcn_mfma_f32_16x16x32_bf16(alo, bf1, acc1, 0, 0, 0);
    acc2 = __builtin_amdgcn_mfma_f32_16x16x32_bf16(ahi, bf2, acc2, 0, 0, 0);
    acc2 = __builtin_amdgcn_mfma_f32_16x16x32_bf16(alo, bf2, acc2, 0, 0, 0);
    acc3 = __builtin_amdgcn_mfma_f32_16x16x32_bf16(ahi, bf3, acc3, 0, 0, 0);
    acc3 = __builtin_amdgcn_mfma_f32_16x16x32_bf16(alo, bf3, acc3, 0, 0, 0);
  }

#pragma unroll
  for (int t = 0; t < 4; ++t) {
    int col = colbase + 16 * t + l15;
    float bv = bias ? bias[col] : 0.0f;
    f32x4 a = (t == 0) ? acc0 : (t == 1) ? acc1 : (t == 2) ? acc2 : acc3;
#pragma unroll
    for (int r = 0; r < 4; ++r) {
      int orow = rowbase + lk * 4 + r;
      if (orow < nrows) {
        float v = a[r] + bv;
        if (BF16OUT) outb[(size_t)orow * HID + col] = __float2bfloat16(v);
        else         outf[(size_t)orow * HID + col] = v;
      }
    }
  }
}

// One wave per dst node; 4 lane-groups of 16; unroll x4 (edges j..j+12 per
// iter, ascending accumulate => bit-exact vs stride-4 loop).
template<bool PROJ>
__global__ void gather_norm_kernel(const int* __restrict__ rowptr,
                                   const uint2* __restrict__ ecol,
                                   const uint4* __restrict__ xwb4,
                                   const float* __restrict__ dinv,
                                   const float* __restrict__ cb,
                                   const float* __restrict__ g,
                                   const float* __restrict__ b,
                                   const float* __restrict__ eW,
                                   const float* __restrict__ rW,
                                   float* __restrict__ outx,
                                   float4* __restrict__ table, int n_nodes) {
  int d = blockIdx.x * 4 + (threadIdx.x >> 6);
  if (d >= n_nodes) return;
  int lane = threadIdx.x & 63;
  int grp = lane >> 4;
  int t = lane & 15;

  float acc[8];
#pragma unroll
  for (int k = 0; k < 8; ++k) acc[k] = 0.0f;

  float wd = dinv[d];
  int beg = rowptr[d], end = rowptr[d + 1];
  int j = beg + grp;
  for (; j + 12 < end; j += 16) {
    uint2 e0 = ecol[j];
    uint2 e1 = ecol[j + 4];
    uint2 e2 = ecol[j + 8];
    uint2 e3 = ecol[j + 12];
    uint4 v0 = xwb4[(size_t)e0.x * 16 + t];
    uint4 v1 = xwb4[(size_t)e1.x * 16 + t];
    uint4 v2 = xwb4[(size_t)e2.x * 16 + t];
    uint4 v3 = xwb4[(size_t)e3.x * 16 + t];
    float w0 = __builtin_bit_cast(float, e0.y);
    float w1 = __builtin_bit_cast(float, e1.y);
    float w2 = __builtin_bit_cast(float, e2.y);
    float w3 = __builtin_bit_cast(float, e3.y);
    acc[0] = fmaf(bf16lo(v0.x), w0, acc[0]);
    acc[1] = fmaf(bf16hi(v0.x), w0, acc[1]);
    acc[2] = fmaf(bf16lo(v0.y), w0, acc[2]);
    acc[3] = fmaf(bf16hi(v0.y), w0, acc[3]);
    acc[4] = fmaf(bf16lo(v0.z), w0, acc[4]);
    acc[5] = fmaf(bf16hi(v0.z), w0, acc[5]);
    acc[6] = fmaf(bf16lo(v0.w), w0, acc[6]);
    acc[7] = fmaf(bf16hi(v0.w), w0, acc[7]);
    acc[0] = fmaf(bf16lo(v1.x), w1, acc[0]);
    acc[1] = fmaf(bf16hi(v1.x), w1, acc[1]);
    acc[2] = fmaf(bf16lo(v1.y), w1, acc[2]);
    acc[3] = fmaf(bf16hi(v1.y), w1, acc[3]);
    acc[4] = fmaf(bf16lo(v1.z), w1, acc[4]);
    acc[5] = fmaf(bf16hi(v1.z), w1, acc[5]);
    acc[6] = fmaf(bf16lo(v1.w), w1, acc[6]);
    acc[7] = fmaf(bf16hi(v1.w), w1, acc[7]);
    acc[0] = fmaf(bf16lo(v2.x), w2, acc[0]);
    acc[1] = fmaf(bf16hi(v2.x), w2, acc[1]);
    acc[2] = fmaf(bf16lo(v2.y), w2, acc[2]);
    acc[3] = fmaf(bf16hi(v2.y), w2, acc[3]);
    acc[4] = fmaf(bf16lo(v2.z), w2, acc[4]);
    acc[5] = fmaf(bf16hi(v2.z), w2, acc[5]);
    acc[6] = fmaf(bf16lo(v2.w), w2, acc[6]);
    acc[7] = fmaf(bf16hi(v2.w), w2, acc[7]);
    acc[0] = fmaf(bf16lo(v3.x), w3, acc[0]);
    acc[1] = fmaf(bf16hi(v3.x), w3, acc[1]);
    acc[2] = fmaf(bf16lo(v3.y), w3, acc[2]);
    acc[3] = fmaf(bf16hi(v3.y), w3, acc[3]);
    acc[4] = fmaf(bf16lo(v3.z), w3, acc[4]);
    acc[5] = fmaf(bf16hi(v3.z), w3, acc[5]);
    acc[6] = fmaf(bf16lo(v3.w), w3, acc[6]);
    acc[7] = fmaf(bf16hi(v3.w), w3, acc[7]);
  }
  for (; j < end; j += 4) {
    uint2 e0 = ecol[j];
    uint4 v0 = xwb4[(size_t)e0.x * 16 + t];
    float w0 = __builtin_bit_cast(float, e0.y);
    acc[0] = fmaf(bf16lo(v0.x), w0, acc[0]);
    acc[1] = fmaf(bf16hi(v0.x), w0, acc[1]);
    acc[2] = fmaf(bf16lo(v0.y), w0, acc[2]);
    acc[3] = fmaf(bf16hi(v0.y), w0, acc[3]);
    acc[4] = fmaf(bf16lo(v0.z), w0, acc[4]);
    acc[5] = fmaf(bf16hi(v0.z), w0, acc[5]);
    acc[6] = fmaf(bf16lo(v0.w), w0, acc[6]);
    acc[7] = fmaf(bf16hi(v0.w), w0, acc[7]);
  }
#pragma unroll
  for (int k = 0; k < 8; ++k) {
    acc[k] += __shfl_xor(acc[k], 16);
    acc[k] += __shfl_xor(acc[k], 32);
  }
  {
    float wself = wd * wd;
    uint4 v = xwb4[(size_t)d * 16 + t];
    acc[0] = fmaf(bf16lo(v.x), wself, acc[0]);
    acc[1] = fmaf(bf16hi(v.x), wself, acc[1]);
    acc[2] = fmaf(bf16lo(v.y), wself, acc[2]);
    acc[3] = fmaf(bf16hi(v.y), wself, acc[3]);
    acc[4] = fmaf(bf16lo(v.z), wself, acc[4]);
    acc[5] = fmaf(bf16hi(v.z), wself, acc[5]);
    acc[6] = fmaf(bf16lo(v.w), wself, acc[6]);
    acc[7] = fmaf(bf16hi(v.w), wself, acc[7]);
    float4 c0 = *reinterpret_cast<const float4*>(cb + 8 * t);
    float4 c1 = *reinterpret_cast<const float4*>(cb + 8 * t + 4);
    acc[0] += c0.x; acc[1] += c0.y; acc[2] += c0.z; acc[3] += c0.w;
    acc[4] += c1.x; acc[5] += c1.y; acc[6] += c1.z; acc[7] += c1.w;
  }
  float s = acc[0] + acc[1] + acc[2] + acc[3] + acc[4] + acc[5] + acc[6] + acc[7];
#pragma unroll
  for (int m = 1; m < 16; m <<= 1) s += __shfl_xor(s, m);
  float mu = s * (1.0f / HID);
  float sq = 0.0f;
#pragma unroll
  for (int k = 0; k < 8; ++k) {
    acc[k] -= mu;
    sq = fmaf(acc[k], acc[k], sq);
  }
#pragma unroll
  for (int m = 1; m < 16; m <<= 1) sq += __shfl_xor(sq, m);
  float rs = rsqrtf(sq * (1.0f / HID) + LN_EPS);
  float4 g0 = *reinterpret_cast<const float4*>(g + 8 * t);
  float4 g1 = *reinterpret_cast<const float4*>(g + 8 * t + 4);
  float4 b0 = *reinterpret_cast<const float4*>(b + 8 * t);
  float4 b1 = *reinterpret_cast<const float4*>(b + 8 * t + 4);
  float o[8];
  o[0] = acc[0] * rs * g0.x + b0.x;
  o[1] = acc[1] * rs * g0.y + b0.y;
  o[2] = acc[2] * rs * g0.z + b0.z;
  o[3] = acc[3] * rs * g0.w + b0.w;
  o[4] = acc[4] * rs * g1.x + b1.x;
  o[5] = acc[5] * rs * g1.y + b1.y;
  o[6] = acc[6] * rs * g1.z + b1.z;
  o[7] = acc[7] * rs * g1.w + b1.w;
#pragma unroll
  for (int k = 0; k < 8; ++k) o[k] = o[k] >= 0.0f ? o[k] : SLOPE * o[k];

  if (!PROJ) {
    if (grp == 0) {
      float4* op = reinterpret_cast<float4*>(outx + (size_t)d * HID + 8 * t);
      op[0] = make_float4(o[0], o[1], o[2], o[3]);
      op[1] = make_float4(o[4], o[5], o[6], o[7]);
    }
  } else {
    float4 eu0 = *reinterpret_cast<const float4*>(eW + 8 * t);
    float4 eu1 = *reinterpret_cast<const float4*>(eW + 8 * t + 4);
    float4 ef0 = *reinterpret_cast<const float4*>(eW + HID + 8 * t);
    float4 ef1 = *reinterpret_cast<const float4*>(eW + HID + 8 * t + 4);
    float4 ru0 = *reinterpret_cast<const float4*>(rW + 8 * t);
    float4 ru1 = *reinterpret_cast<const float4*>(rW + 8 * t + 4);
    float4 rf0 = *reinterpret_cast<const float4*>(rW + HID + 8 * t);
    float4 rf1 = *reinterpret_cast<const float4*>(rW + HID + 8 * t + 4);
    float pa = o[0]*eu0.x + o[1]*eu0.y + o[2]*eu0.z + o[3]*eu0.w
             + o[4]*eu1.x + o[5]*eu1.y + o[6]*eu1.z + o[7]*eu1.w;
    float pb = o[0]*ef0.x + o[1]*ef0.y + o[2]*ef0.z + o[3]*ef0.w
             + o[4]*ef1.x + o[5]*ef1.y + o[6]*ef1.z + o[7]*ef1.w;
    float pc = o[0]*ru0.x + o[1]*ru0.y + o[2]*ru0.z + o[3]*ru0.w
             + o[4]*ru1.x + o[5]*ru1.y + o[6]*ru1.z + o[7]*ru1.w;
    float pd = o[0]*rf0.x + o[1]*rf0.y + o[2]*rf0.z + o[3]*rf0.w
             + o[4]*rf1.x + o[5]*rf1.y + o[6]*rf1.z + o[7]*rf1.w;
#pragma unroll
    for (int m = 1; m < 16; m <<= 1) {
      pa += __shfl_xor(pa, m);
      pb += __shfl_xor(pb, m);
      pc += __shfl_xor(pc, m);
      pd += __shfl_xor(pd, m);
    }
    if (lane == 0) table[d] = make_float4(pa, pb, pc, pd);
  }
}

// one thread per 2 prediction pairs (vectorized index loads / stores)
__global__ void pair_kernel(const int* __restrict__ eu, const int* __restrict__ ef,
                            const float4* __restrict__ table,
                            const float* __restrict__ eb, const float* __restrict__ rb,
                            float* __restrict__ out_exist, float* __restrict__ out_rating,
                            int Ep) {
  int i = blockIdx.x * blockDim.x + threadIdx.x;
  int base = 2 * i;
  if (base >= Ep) return;
  float ebv = eb[0], rbv = rb[0];
  if (base + 1 < Ep) {
    int2 u2 = *reinterpret_cast<const int2*>(&eu[base]);
    int2 f2 = *reinterpret_cast<const int2*>(&ef[base]);
    float4 tu0 = table[u2.x];
    float4 tf0 = table[f2.x];
    float4 tu1 = table[u2.y];
    float4 tf1 = table[f2.y];
    float2 ex, ra;
    ex.x = 1.0f / (1.0f + expf(-(tu0.x + tf0.y + ebv)));
    ex.y = 1.0f / (1.0f + expf(-(tu1.x + tf1.y + ebv)));
    ra.x = 1.0f + 4.0f / (1.0f + expf(-(tu0.z + tf0.w + rbv)));
    ra.y = 1.0f + 4.0f / (1.0f + expf(-(tu1.z + tf1.w + rbv)));
    *reinterpret_cast<float2*>(&out_exist[base]) = ex;
    *reinterpret_cast<float2*>(&out_rating[base]) = ra;
  } else {
    float4 tu = table[eu[base]];
    float4 tf = table[ef[base]];
    out_exist[base]  = 1.0f / (1.0f + expf(-(tu.x + tf.y + ebv)));
    out_rating[base] = 1.0f + 4.0f / (1.0f + expf(-(tu.z + tf.w + rbv)));
  }
}

extern "C" void kernel_launch(void* const* d_in, const int* in_sizes, int n_in,
                              void* d_out, int out_size, void* d_ws, size_t ws_size,
                              hipStream_t stream) {
  const float* u_feat = (const float*)d_in[0];
  const float* f_feat = (const float*)d_in[1];
  const int*   ei     = (const int*)d_in[2];
  const int*   eu     = (const int*)d_in[3];
  const int*   ef     = (const int*)d_in[4];
  const float* u_W  = (const float*)d_in[5];
  const float* u_b  = (const float*)d_in[6];
  const float* f_W  = (const float*)d_in[7];
  const float* f_b  = (const float*)d_in[8];
  const float* c1_W = (const float*)d_in[9];
  const float* c1_b = (const float*)d_in[10];
  const float* c2_W = (const float*)d_in[11];
  const float* c2_b = (const float*)d_in[12];
  const float* n1_g = (const float*)d_in[13];
  const float* n1_b = (const float*)d_in[14];
  const float* n2_g = (const float*)d_in[15];
  const float* n2_b = (const float*)d_in[16];
  const float* e_W  = (const float*)d_in[17];
  const float* e_b  = (const float*)d_in[18];
  const float* r_W  = (const float*)d_in[19];
  const float* r_b  = (const float*)d_in[20];

  int n_u = in_sizes[0] / 64;
  int n_f = in_sizes[1] / HID;
  int n   = n_u + n_f;
  int E   = in_sizes[2] / 2;
  int Ep  = in_sizes[3];
  int nbuck  = (n + (1 << BSHIFT) - 1) >> BSHIFT;
  int nchunk = (E + CHUNK - 1) / CHUNK;
  int m      = nbuck * nchunk;

  const int* src = ei;
  const int* dst = ei + E;

  float*        x      = (float*)d_ws;                            // n*HID f32
  unsigned int* xwb    = (unsigned int*)(x + (size_t)n * HID);    // n*HID/2 uint
  float4*       table  = (float4*)(xwb + (size_t)n * (HID / 2));  // n float4
  unsigned int* ebuf   = (unsigned int*)(table + n);              // E uint (packed)
  uint2*        ecol   = (uint2*)(ebuf + E);                      // E uint2 (src, w)
  float*        dinv   = (float*)(ecol + E);                      // n f32
  int*          rowptr = (int*)(dinv + n);                        // n+1 int
  int*          cntM   = rowptr + n + 1;                          // m int
  int*          scanM  = cntM + m;                                // m+1 int
  int*          blocksum = scanM + m + 1;                         // NB_SCAN int
  unsigned int* wt_u1  = (unsigned int*)(blocksum + NB_SCAN);     // 128*32 uint
  unsigned int* wt_f1  = wt_u1 + 128 * 32;                        // 128*64 uint
  unsigned int* wt_c2  = wt_f1 + 128 * 64;                        // 128*64 uint
  float*        bc_u   = (float*)(wt_c2 + 128 * 64);              // 128 f32
  float*        bc_f   = bc_u + 128;                              // 128 f32

  // ---- fused weight prep + per-chunk histogram (one launch) ----
  prep_hist_kernel<<<WPREP_BLOCKS + nchunk, 256, 0, stream>>>(
      u_W, f_W, c1_W, c2_W, u_b, f_b, wt_u1, wt_f1, wt_c2, bc_u, bc_f,
      dst, cntM, E, nbuck, nchunk);

  // ---- scan (pass2 folded into pass3) + deterministic scatter ----
  scan_pass1<<<NB_SCAN, NT_SCAN, 0, stream>>>(cntM, blocksum, m);
  scan_pass3<<<NB_SCAN, NT_SCAN, 0, stream>>>(cntM, blocksum, scanM, m);
  scatter_chunk_kernel<<<nchunk, 256, 0, stream>>>(src, dst, scanM, ebuf, E, nbuck, nchunk);

  // ---- per-node rowptr/dinv, then per-bucket CSR fill ----
  deg_rowptr_kernel<<<nbuck, 256, 0, stream>>>(ebuf, scanM, rowptr, dinv,
                                               n, nbuck, nchunk, E);
  fill_bucket_kernel<<<nbuck, 256, 0, stream>>>(ebuf, scanM, rowptr, dinv, ecol,
                                                n, nchunk);

  // ---- layer 1: composed dense (embed + conv1 linear) -> xwb ----
  dense_mfma_kernel<64, true><<<(n_u + 31) / 32, 256, 0, stream>>>(
      u_feat, wt_u1, bc_u, nullptr, (__hip_bfloat16*)xwb, n_u);
  dense_mfma_kernel<128, true><<<(n_f + 31) / 32, 256, 0, stream>>>(
      f_feat, wt_f1, bc_f, nullptr, ((__hip_bfloat16*)xwb) + (size_t)n_u * HID, n_f);
  gather_norm_kernel<false><<<(n + 3) / 4, 256, 0, stream>>>(
      rowptr, ecol, (const uint4*)xwb, dinv, c1_b, n1_g, n1_b,
      nullptr, nullptr, x, nullptr, n);

  // ---- layer 2 (fused prediction-head projection) ----
  dense_mfma_kernel<128, true><<<(n + 31) / 32, 256, 0, stream>>>(
      x, wt_c2, nullptr, nullptr, (__hip_bfloat16*)xwb, n);
  gather_norm_kernel<true><<<(n + 3) / 4, 256, 0, stream>>>(
      rowptr, ecol, (const uint4*)xwb, dinv, c2_b, n2_g, n2_b,
      e_W, r_W, nullptr, table, n);

  // ---- per-pair combine ----
  float* out_exist  = (float*)d_out;
  float* out_rating = out_exist + Ep;
  pair_kernel<<<((Ep + 1) / 2 + 255) / 256, 256, 0, stream>>>(
      eu, ef, table, e_b, r_b, out_exist, out_rating, Ep);
}